// Round 7
// baseline (2253.454 us; speedup 1.0000x reference)
//
#include <hip/hip_runtime.h>
#include <math.h>

namespace {

constexpr int TNZ = 8, TNY = 512, TNX = 512, TM = 128;
constexpr int PITCH = 130;                 // float2 pitch of LDS transpose buffer
constexpr float INV_N2 = 1.0f / (TM * TM);
constexpr float EPSV = 1e-10f;

// ---- compile-time trig (double Taylor, exact to fp32) ----
constexpr double PI_D = 3.14159265358979323846264338327950288;
constexpr double tsin(double x) {
  double t = x, s = x, x2 = x * x;
  for (int n = 1; n <= 24; ++n) { t *= -x2 / double((2 * n) * (2 * n + 1)); s += t; }
  return s;
}
constexpr double tcos(double x) {
  double t = 1.0, s = 1.0, x2 = x * x;
  for (int n = 1; n <= 24; ++n) { t *= -x2 / double((2 * n - 1) * (2 * n)); s += t; }
  return s;
}
struct Tw { float c[64], s[64]; };
constexpr Tw mkTw() {
  Tw T{};
  for (int m = 0; m < 64; ++m) {
    double a = -2.0 * PI_D * (double)m / 128.0;
    T.c[m] = (float)tcos(a); T.s[m] = (float)tsin(a);
  }
  return T;
}
constexpr Tw TW = mkTw();

constexpr int crev5(int j) {
  return ((j & 1) << 4) | ((j & 2) << 2) | (j & 4) | ((j & 8) >> 2) | ((j & 16) >> 4);
}
// H phase: ph(j, r2s) = PKF*iy^2, iy = 4*rev5(j) + r2s - 128*[rev5(j)>=16]
//        = K0[j] + K1[j]*r2s + PKF*r2s^2   (last term folded into thread base)
constexpr double PKF_D = -PI_D * 0.025 * 10.0 / (128.0 * 0.2) / (128.0 * 0.2);
struct Hp { float k0[32], k1[32]; };
constexpr Hp mkHp() {
  Hp P{};
  for (int j = 0; j < 32; ++j) {
    int r5 = crev5(j);
    int C = 4 * r5 - ((r5 & 16) ? 128 : 0);
    P.k0[j] = (float)(PKF_D * C * C);
    P.k1[j] = (float)(2.0 * PKF_D * C);
  }
  return P;
}
constexpr Hp HP = mkHp();
constexpr float PKF_F = (float)PKF_D;

__device__ __forceinline__ float2 cmul(float2 a, float2 b) {
  return make_float2(a.x * b.x - a.y * b.y, a.x * b.y + a.y * b.x);
}
__device__ __forceinline__ float2 cmulc(float2 a, float2 b) {  // a * conj(b)
  return make_float2(a.x * b.x + a.y * b.y, a.y * b.x - a.x * b.y);
}
__device__ __forceinline__ float2 shxor(float2 v, int m) {
  return make_float2(__shfl_xor(v.x, m, 64), __shfl_xor(v.y, m, 64));
}
// Column swizzle: fold segment bits (5-6) of the column index into bits 0-1.
__device__ __forceinline__ int swc(int col) { return col ^ ((col & 0x60) >> 5); }
__device__ __forceinline__ int rev7(int n) {
  return ((n & 1) << 6) | ((n & 2) << 4) | ((n & 4) << 2) | (n & 8) |
         ((n & 16) >> 2) | ((n & 32) >> 4) | ((n & 64) >> 6);
}

// ---- local (in-thread) radix-2 stages; twiddles are compile-time literals ----
template <int H>
__device__ __forceinline__ void dif_local(float2 (&X)[32]) {
#pragma unroll
  for (int m = 0; m < H; ++m) {
    const float2 W = make_float2(TW.c[m * (64 / H)], TW.s[m * (64 / H)]);
#pragma unroll
    for (int b = 0; b < 32; b += 2 * H) {
      const int j = b + m;
      float2 A = X[j], B = X[j + H];
      X[j] = make_float2(A.x + B.x, A.y + B.y);
      float2 d = make_float2(A.x - B.x, A.y - B.y);
      X[j + H] = cmul(d, W);
    }
  }
}
template <int H>
__device__ __forceinline__ void dit_local(float2 (&X)[32]) {
#pragma unroll
  for (int m = 0; m < H; ++m) {
    const float2 W = make_float2(TW.c[m * (64 / H)], TW.s[m * (64 / H)]);
#pragma unroll
    for (int b = 0; b < 32; b += 2 * H) {
      const int j = b + m;
      float2 A = X[j];
      float2 B = cmulc(X[j + H], W);
      X[j] = make_float2(A.x + B.x, A.y + B.y);
      X[j + H] = make_float2(A.x - B.x, A.y - B.y);
    }
  }
}

// Forward DIF FFT-128. Thread segment s (0..3) owns n = 32*s + j.
__device__ __forceinline__ void dif128(float2 (&X)[32], int s) {
  const bool b2 = (s & 2) != 0, b1 = (s & 1) != 0;
  // stage h=64, partner lane ^2 ; W = TW[j] * (b1 ? -i : 1)
#pragma unroll
  for (int j = 0; j < 32; ++j) {
    float2 o = shxor(X[j], 2);
    float Wr = b1 ? TW.s[j] : TW.c[j];
    float Wi = b1 ? -TW.c[j] : TW.s[j];
    float2 sum = make_float2(X[j].x + o.x, X[j].y + o.y);
    float2 dif = make_float2(o.x - X[j].x, o.y - X[j].y);
    float2 pr = cmul(dif, make_float2(Wr, Wi));
    X[j] = b2 ? pr : sum;
  }
  // stage h=32, partner ^1 ; W = TW[2j] (uniform literal)
#pragma unroll
  for (int j = 0; j < 32; ++j) {
    float2 o = shxor(X[j], 1);
    const float2 W = make_float2(TW.c[2 * j], TW.s[2 * j]);
    float2 sum = make_float2(X[j].x + o.x, X[j].y + o.y);
    float2 dif = make_float2(o.x - X[j].x, o.y - X[j].y);
    float2 pr = cmul(dif, W);
    X[j] = b1 ? pr : sum;
  }
  dif_local<16>(X);
  dif_local<8>(X);
  dif_local<4>(X);
  dif_local<2>(X);
#pragma unroll
  for (int b = 0; b < 32; b += 2) {  // h=1, W=1
    float2 A = X[b], B = X[b + 1];
    X[b] = make_float2(A.x + B.x, A.y + B.y);
    X[b + 1] = make_float2(A.x - B.x, A.y - B.y);
  }
}

// Inverse (DIT) FFT-128: exact inverse network (bitrev in, natural out, unscaled)
__device__ __forceinline__ void dit128(float2 (&X)[32], int s) {
  const bool b2 = (s & 2) != 0, b1 = (s & 1) != 0;
#pragma unroll
  for (int b = 0; b < 32; b += 2) {  // h=1
    float2 A = X[b], B = X[b + 1];
    X[b] = make_float2(A.x + B.x, A.y + B.y);
    X[b + 1] = make_float2(A.x - B.x, A.y - B.y);
  }
  dit_local<2>(X);
  dit_local<4>(X);
  dit_local<8>(X);
  dit_local<16>(X);
  // cross h=32, partner ^1 : W = TW[2j], conj applied
  {
    const float sg = b1 ? -1.0f : 1.0f;
#pragma unroll
    for (int j = 0; j < 32; ++j) {
      float2 o = shxor(X[j], 1);
      const float2 W = make_float2(TW.c[2 * j], TW.s[2 * j]);
      float2 vin = b1 ? X[j] : o;  // upper element value
      float2 u = b1 ? o : X[j];    // lower element value
      float2 B = cmulc(vin, W);
      X[j] = make_float2(fmaf(sg, B.x, u.x), fmaf(sg, B.y, u.y));
    }
  }
  // cross h=64, partner ^2 : cW = conj(TW[j] * (b1 ? -i : 1))
  {
    const float sg = b2 ? -1.0f : 1.0f;
#pragma unroll
    for (int j = 0; j < 32; ++j) {
      float2 o = shxor(X[j], 2);
      float cWr = b1 ? TW.s[j] : TW.c[j];
      float cWi = b1 ? TW.c[j] : -TW.s[j];
      float2 vin = b2 ? X[j] : o;
      float2 u = b2 ? o : X[j];
      float2 B = cmul(vin, make_float2(cWr, cWi));
      X[j] = make_float2(fmaf(sg, B.x, u.x), fmaf(sg, B.y, u.y));
    }
  }
}

// One block = one (k, mode). Accumulates |psi_f|^2 into out via atomicAdd.
__global__ __launch_bounds__(512, 1)
void msp_mode(const float* __restrict__ V, const float* __restrict__ Pre,
              const float* __restrict__ Pim, const int* __restrict__ pos,
              float* __restrict__ out) {
  __shared__ float2 fld[TM * PITCH];  // 133,120 B transpose buffer

  const int t = threadIdx.x;
  const int k = blockIdx.x >> 2;
  const int m = blockIdx.x & 3;
  const int s = t & 3;    // segment: owns x = 32*s + j
  const int rc = t >> 2;  // row (row passes) / col (col passes), 0..127

  const int p0 = pos[2 * k];
  const int p1 = pos[2 * k + 1];

  // per-thread H base: phx = PKF*ix^2 (kx = rev7(rc)), + PKF*r2s^2 term
  const int kx = rev7(rc);
  const int ixf = kx - ((kx & 64) ? 128 : 0);
  const int r2s = ((s & 1) << 1) | (s >> 1);  // rev2(s)
  const float r2sf = (float)r2s;
  const float hbase = PKF_F * (float)(ixf * ixf) + PKF_F * r2sf * r2sf;

  float2 X[32];

  // load probe mode m (row ownership: row rc, cols 32s..32s+31)
  {
    const float* pr = Pre + ((m * TM + rc) * TM + 32 * s);
    const float* pi = Pim + ((m * TM + rc) * TM + 32 * s);
#pragma unroll
    for (int q = 0; q < 8; ++q) {
      float4 a = reinterpret_cast<const float4*>(pr)[q];
      float4 b = reinterpret_cast<const float4*>(pi)[q];
      X[4 * q + 0] = make_float2(a.x, b.x);
      X[4 * q + 1] = make_float2(a.y, b.y);
      X[4 * q + 2] = make_float2(a.z, b.z);
      X[4 * q + 3] = make_float2(a.w, b.w);
    }
  }

  for (int z = 0; z < TNZ; ++z) {
    // multiply by T = exp(i*V), chunked to cap in-flight load temps
    {
      const float* vb = V + ((z * TNY + (p0 + rc)) * TNX + p1 + 32 * s);
#pragma unroll
      for (int c = 0; c < 2; ++c) {
#pragma unroll
        for (int u = 0; u < 16; ++u) {
          const int j = 16 * c + u;
          float v = vb[j];
          float sv, cv;
          __sincosf(v, &sv, &cv);
          X[j] = cmul(X[j], make_float2(cv, sv));
        }
        __builtin_amdgcn_sched_barrier(0);
      }
    }
    dif128(X, s);  // rows
    // transpose rows -> cols (swizzled b64)
    __syncthreads();
#pragma unroll
    for (int j = 0; j < 32; ++j) fld[rc * PITCH + swc(32 * s + j)] = X[j];
    __syncthreads();
#pragma unroll
    for (int j = 0; j < 32; ++j) X[j] = fld[(32 * s + j) * PITCH + swc(rc)];

    dif128(X, s);  // cols

    if (z == TNZ - 1) break;  // last slice: no propagation

    // H multiply at (ky=rev7(32s+j), kx=rev7(rc)); recomputed per z
    // (opaque hbase defeats LICM so 64 regs of hy aren't pinned)
    {
      float bz = hbase;
      asm volatile("" : "+v"(bz));
#pragma unroll
      for (int j = 0; j < 32; ++j) {
        float ph = bz + HP.k0[j] + HP.k1[j] * r2sf;
        float sp, cp;
        __sincosf(ph, &sp, &cp);
        X[j] = cmul(X[j], make_float2(cp * INV_N2, sp * INV_N2));
      }
    }

    dit128(X, s);  // cols inverse
    // transpose cols -> rows (swizzled b64)
    __syncthreads();
#pragma unroll
    for (int j = 0; j < 32; ++j) fld[(32 * s + j) * PITCH + swc(rc)] = X[j];
    __syncthreads();
#pragma unroll
    for (int j = 0; j < 32; ++j) X[j] = fld[rc * PITCH + swc(32 * s + j)];
    dit128(X, s);  // rows inverse
  }

  // un-bit-reverse |X|^2 via LDS, then coalesced global atomic accumulate
  __syncthreads();
  float* fldf = reinterpret_cast<float*>(fld);
#pragma unroll
  for (int j = 0; j < 32; ++j) {
    const int ky = (crev5(j) << 2) | r2s;  // rev7(32s+j)
    fldf[ky * PITCH + kx] = fmaf(X[j].x, X[j].x, X[j].y * X[j].y);
  }
  __syncthreads();
  float* ob = out + k * (TM * TM);
#pragma unroll
  for (int i = 0; i < 32; ++i) {
    const int idx = t + 512 * i;
    const int yy = idx >> 7, xx = idx & 127;
    atomicAdd(&ob[idx], fldf[yy * PITCH + xx]);
  }
}

__global__ __launch_bounds__(256) void zero_k(float4* __restrict__ p, int n4) {
  const int i = blockIdx.x * 256 + threadIdx.x;
  if (i < n4) p[i] = make_float4(0.f, 0.f, 0.f, 0.f);
}

__global__ __launch_bounds__(256) void sqrt_k(float* __restrict__ p, int n) {
  const int i = blockIdx.x * 256 + threadIdx.x;
  if (i < n) p[i] = sqrtf(EPSV + p[i] * INV_N2);  // ortho: 1/N^2 on |.|^2
}

}  // namespace

extern "C" void kernel_launch(void* const* d_in, const int* in_sizes, int n_in,
                              void* d_out, int out_size, void* d_ws, size_t ws_size,
                              hipStream_t stream) {
  (void)in_sizes; (void)n_in; (void)d_ws; (void)ws_size;
  const float* V = (const float*)d_in[0];
  const float* Pre = (const float*)d_in[1];
  const float* Pim = (const float*)d_in[2];
  const int* pos = (const int*)d_in[3];
  float* out = (float*)d_out;
  const int n = out_size;  // 256*128*128
  const int n4 = n >> 2;
  zero_k<<<dim3((n4 + 255) / 256), dim3(256), 0, stream>>>((float4*)out, n4);
  msp_mode<<<dim3(1024), dim3(512), 0, stream>>>(V, Pre, Pim, pos, out);
  sqrt_k<<<dim3((n + 255) / 256), dim3(256), 0, stream>>>(out, n);
}

// Round 8
// 2019.266 us; speedup vs baseline: 1.1160x; 1.1160x over previous
//
#include <hip/hip_runtime.h>
#include <math.h>

namespace {

constexpr int TNZ = 8, TNY = 512, TNX = 512, TM = 128;
constexpr int PITCH = 130;                 // float2 pitch of LDS transpose buffer
constexpr float F0 = 1.0f / (TM * 0.2f);   // fftfreq step 1/(M*dr)
constexpr float PK = -3.14159265358979323846f * 0.025f * 10.0f;  // -pi*lambda*dz
constexpr float INV_N2 = 1.0f / (TM * TM);
constexpr float EPSV = 1e-10f;

__device__ __forceinline__ float2 cmul(float2 a, float2 b) {
  return make_float2(a.x * b.x - a.y * b.y, a.x * b.y + a.y * b.x);
}
__device__ __forceinline__ float2 cmulc(float2 a, float2 b) {  // a * conj(b)
  return make_float2(a.x * b.x + a.y * b.y, a.y * b.x - a.x * b.y);
}
__device__ __forceinline__ float2 shxor(float2 v, int m) {
  return make_float2(__shfl_xor(v.x, m, 64), __shfl_xor(v.y, m, 64));
}
// Column swizzle: fold segment bits (5-6) of the column index into bits 0-1.
__device__ __forceinline__ int swc(int col) { return col ^ ((col & 0x60) >> 5); }
__device__ __forceinline__ int rev7(int n) {
  return ((n & 1) << 6) | ((n & 2) << 4) | ((n & 4) << 2) | (n & 8) |
         ((n & 16) >> 2) | ((n & 32) >> 4) | ((n & 64) >> 6);
}
__device__ __forceinline__ int opq(int v) {  // defeat LICM/CSE on derived loads
  asm volatile("" : "+v"(v));
  return v;
}

// ---- local (in-thread) radix-2 stages over 32 elements ----
// twd[m] = exp(-2*pi*i*m/128), m < 64 ; toff = opaque 0 (anti-hoist)
template <int H>
__device__ __forceinline__ void dif_local(float2 (&X)[32], const float2* twd,
                                          int toff) {
#pragma unroll
  for (int m = 0; m < H; ++m) {
    float2 W = twd[toff + m * (64 / H)];
#pragma unroll
    for (int b = 0; b < 32; b += 2 * H) {
      const int j = b + m;
      float2 A = X[j], B = X[j + H];
      X[j] = make_float2(A.x + B.x, A.y + B.y);
      float2 d = make_float2(A.x - B.x, A.y - B.y);
      X[j + H] = cmul(d, W);
    }
    if constexpr (H == 16) {
      if ((m & 7) == 7) __builtin_amdgcn_sched_barrier(0);
    }
  }
  __builtin_amdgcn_sched_barrier(0);
}
template <int H>
__device__ __forceinline__ void dit_local(float2 (&X)[32], const float2* twd,
                                          int toff) {
#pragma unroll
  for (int m = 0; m < H; ++m) {
    float2 W = twd[toff + m * (64 / H)];
#pragma unroll
    for (int b = 0; b < 32; b += 2 * H) {
      const int j = b + m;
      float2 A = X[j];
      float2 B = cmulc(X[j + H], W);
      X[j] = make_float2(A.x + B.x, A.y + B.y);
      X[j + H] = make_float2(A.x - B.x, A.y - B.y);
    }
    if constexpr (H == 16) {
      if ((m & 7) == 7) __builtin_amdgcn_sched_barrier(0);
    }
  }
  __builtin_amdgcn_sched_barrier(0);
}

// Forward DIF FFT-128. Thread segment s (0..3) owns n = 32*s + j.
// Natural order in, bit-reversed positions out.
__device__ __forceinline__ void dif128(float2 (&X)[32], const float2* twd, int s) {
  const int toff = opq(0);  // per-inline-instance opaque: no CSE across calls
  const bool b2 = (s & 2) != 0, b1 = (s & 1) != 0;
  // stage h=64, partner lane ^2 ; W = twd[32*(s&1)+j] = twd[j] * (b1 ? -i : 1)
#pragma unroll
  for (int c = 0; c < 4; ++c) {
#pragma unroll
    for (int u = 0; u < 8; ++u) {
      const int j = 8 * c + u;
      float2 o = shxor(X[j], 2);
      float2 tw = twd[toff + j];
      float2 W = b1 ? make_float2(tw.y, -tw.x) : tw;
      float2 sum = make_float2(X[j].x + o.x, X[j].y + o.y);
      float2 dif = make_float2(o.x - X[j].x, o.y - X[j].y);
      float2 pr = cmul(dif, W);
      X[j] = b2 ? pr : sum;
    }
    __builtin_amdgcn_sched_barrier(0);
  }
  // stage h=32, partner ^1 ; W = W64^j = twd[2j] (wave-uniform)
#pragma unroll
  for (int c = 0; c < 4; ++c) {
#pragma unroll
    for (int u = 0; u < 8; ++u) {
      const int j = 8 * c + u;
      float2 o = shxor(X[j], 1);
      float2 W = twd[toff + 2 * j];
      float2 sum = make_float2(X[j].x + o.x, X[j].y + o.y);
      float2 dif = make_float2(o.x - X[j].x, o.y - X[j].y);
      float2 pr = cmul(dif, W);
      X[j] = b1 ? pr : sum;
    }
    __builtin_amdgcn_sched_barrier(0);
  }
  dif_local<16>(X, twd, toff);
  dif_local<8>(X, twd, toff);
  dif_local<4>(X, twd, toff);
  dif_local<2>(X, twd, toff);
#pragma unroll
  for (int b = 0; b < 32; b += 2) {  // h=1, W=1
    float2 A = X[b], B = X[b + 1];
    X[b] = make_float2(A.x + B.x, A.y + B.y);
    X[b + 1] = make_float2(A.x - B.x, A.y - B.y);
  }
}

// Inverse (DIT) FFT-128: exact inverse network (bitrev in, natural out, unscaled)
__device__ __forceinline__ void dit128(float2 (&X)[32], const float2* twd, int s) {
  const int toff = opq(0);
  const bool b2 = (s & 2) != 0, b1 = (s & 1) != 0;
#pragma unroll
  for (int b = 0; b < 32; b += 2) {  // h=1
    float2 A = X[b], B = X[b + 1];
    X[b] = make_float2(A.x + B.x, A.y + B.y);
    X[b + 1] = make_float2(A.x - B.x, A.y - B.y);
  }
  dit_local<2>(X, twd, toff);
  dit_local<4>(X, twd, toff);
  dit_local<8>(X, twd, toff);
  dit_local<16>(X, twd, toff);
  // cross h=32, partner ^1 : W = twd[2j], conj applied
  {
    const float sg = b1 ? -1.0f : 1.0f;
#pragma unroll
    for (int c = 0; c < 4; ++c) {
#pragma unroll
      for (int u = 0; u < 8; ++u) {
        const int j = 8 * c + u;
        float2 o = shxor(X[j], 1);
        float2 W = twd[toff + 2 * j];
        float2 vin = b1 ? X[j] : o;  // upper element value
        float2 uu = b1 ? o : X[j];   // lower element value
        float2 B = cmulc(vin, W);
        X[j] = make_float2(fmaf(sg, B.x, uu.x), fmaf(sg, B.y, uu.y));
      }
      __builtin_amdgcn_sched_barrier(0);
    }
  }
  // cross h=64, partner ^2 : cW = conj(twd[j] * (b1 ? -i : 1))
  {
    const float sg = b2 ? -1.0f : 1.0f;
#pragma unroll
    for (int c = 0; c < 4; ++c) {
#pragma unroll
      for (int u = 0; u < 8; ++u) {
        const int j = 8 * c + u;
        float2 o = shxor(X[j], 2);
        float2 tw = twd[toff + j];
        float2 cW = b1 ? make_float2(tw.y, tw.x) : make_float2(tw.x, -tw.y);
        float2 vin = b2 ? X[j] : o;
        float2 uu = b2 ? o : X[j];
        float2 B = cmul(vin, cW);
        X[j] = make_float2(fmaf(sg, B.x, uu.x), fmaf(sg, B.y, uu.y));
      }
      __builtin_amdgcn_sched_barrier(0);
    }
  }
}

// One block = one (k, mode). Accumulates |psi_f|^2 into out via atomicAdd.
__global__ __launch_bounds__(512, 1)
void msp_mode(const float* __restrict__ V, const float* __restrict__ Pre,
              const float* __restrict__ Pim, const int* __restrict__ pos,
              float* __restrict__ out) {
  __shared__ float2 fld[TM * PITCH];  // 133,120 B transpose buffer
  __shared__ float2 twd[64];
  __shared__ float2 hyt[4 * 33];  // hy for storage idx n=32s+j at [s*33+j]

  const int t = threadIdx.x;
  const int k = blockIdx.x >> 2;
  const int m = blockIdx.x & 3;
  const int s = t & 3;    // segment: owns x = 32*s + j
  const int rc = t >> 2;  // row (row passes) / col (col passes), 0..127

  if (t < 64) {
    float ang = -6.28318530717958647692f * (float)t / 128.0f;
    twd[t] = make_float2(cosf(ang), sinf(ang));
  }
  if (t < 128) {
    const int ky = rev7(t);
    const int iy = ky - ((ky & 64) ? 128 : 0);
    const float fy = iy * F0;
    const float ph = PK * fy * fy;
    hyt[(t >> 5) * 33 + (t & 31)] = make_float2(cosf(ph), sinf(ph));
  }
  __syncthreads();

  const int p0 = pos[2 * k];
  const int p1 = pos[2 * k + 1];

  // per-thread H x-factor: kx = bitrev7(rc); fold ifft 1/N^2 into it
  const int kx = rev7(rc);
  const int ixf = kx - ((kx & 64) ? 128 : 0);
  const float fx2 = (ixf * F0) * (ixf * F0);
  const float phx = PK * fx2;
  const float2 hxv = make_float2(cosf(phx) * INV_N2, sinf(phx) * INV_N2);

  float2 X[32];

  // load probe mode m (row ownership: row rc, cols 32s..32s+31)
  {
    const float* pr = Pre + ((m * TM + rc) * TM + 32 * s);
    const float* pi = Pim + ((m * TM + rc) * TM + 32 * s);
#pragma unroll
    for (int q = 0; q < 8; ++q) {
      float4 a = reinterpret_cast<const float4*>(pr)[q];
      float4 b = reinterpret_cast<const float4*>(pi)[q];
      X[4 * q + 0] = make_float2(a.x, b.x);
      X[4 * q + 1] = make_float2(a.y, b.y);
      X[4 * q + 2] = make_float2(a.z, b.z);
      X[4 * q + 3] = make_float2(a.w, b.w);
    }
  }

  for (int z = 0; z < TNZ; ++z) {
    // multiply by T = exp(i*V), chunked to cap in-flight load temps
    {
      const float* vb = V + ((z * TNY + (p0 + rc)) * TNX + p1 + 32 * s);
#pragma unroll
      for (int c = 0; c < 2; ++c) {
#pragma unroll
        for (int u = 0; u < 16; ++u) {
          const int j = 16 * c + u;
          float v = vb[j];
          float sv, cv;
          __sincosf(v, &sv, &cv);
          X[j] = cmul(X[j], make_float2(cv, sv));
        }
        __builtin_amdgcn_sched_barrier(0);
      }
    }
    dif128(X, twd, s);  // rows
    // transpose rows -> cols (swizzled b64)
    __syncthreads();
#pragma unroll
    for (int j = 0; j < 32; ++j) fld[rc * PITCH + swc(32 * s + j)] = X[j];
    __syncthreads();
#pragma unroll
    for (int j = 0; j < 32; ++j) X[j] = fld[(32 * s + j) * PITCH + swc(rc)];

    dif128(X, twd, s);  // cols

    if (z == TNZ - 1) break;  // last slice: no propagation

    // H multiply at (ky=rev7(32s+j), kx=rev7(rc)); opaque base defeats LICM
    {
      const int hoff = opq(s * 33);
#pragma unroll
      for (int c = 0; c < 4; ++c) {
#pragma unroll
        for (int u = 0; u < 8; ++u) {
          const int j = 8 * c + u;
          float2 hy = hyt[hoff + j];
          X[j] = cmul(cmul(X[j], hy), hxv);
        }
        __builtin_amdgcn_sched_barrier(0);
      }
    }

    dit128(X, twd, s);  // cols inverse
    // transpose cols -> rows (swizzled b64)
    __syncthreads();
#pragma unroll
    for (int j = 0; j < 32; ++j) fld[(32 * s + j) * PITCH + swc(rc)] = X[j];
    __syncthreads();
#pragma unroll
    for (int j = 0; j < 32; ++j) X[j] = fld[rc * PITCH + swc(32 * s + j)];
    dit128(X, twd, s);  // rows inverse
  }

  // un-bit-reverse |X|^2 via LDS, then coalesced global atomic accumulate
  __syncthreads();
  float* fldf = reinterpret_cast<float*>(fld);
  const int r2s = ((s & 1) << 1) | (s >> 1);  // rev2(s)
#pragma unroll
  for (int j = 0; j < 32; ++j) {
    const int r5 = ((j & 1) << 4) | ((j & 2) << 2) | (j & 4) | ((j & 8) >> 2) |
                   ((j & 16) >> 4);
    const int ky = (r5 << 2) | r2s;  // rev7(32s+j)
    fldf[ky * PITCH + kx] = fmaf(X[j].x, X[j].x, X[j].y * X[j].y);
  }
  __syncthreads();
  float* ob = out + k * (TM * TM);
#pragma unroll
  for (int i = 0; i < 32; ++i) {
    const int idx = t + 512 * i;
    const int yy = idx >> 7, xx = idx & 127;
    atomicAdd(&ob[idx], fldf[yy * PITCH + xx]);
  }
}

__global__ __launch_bounds__(256) void zero_k(float4* __restrict__ p, int n4) {
  const int i = blockIdx.x * 256 + threadIdx.x;
  if (i < n4) p[i] = make_float4(0.f, 0.f, 0.f, 0.f);
}

__global__ __launch_bounds__(256) void sqrt_k(float* __restrict__ p, int n) {
  const int i = blockIdx.x * 256 + threadIdx.x;
  if (i < n) p[i] = sqrtf(EPSV + p[i] * INV_N2);  // ortho: 1/N^2 on |.|^2
}

}  // namespace

extern "C" void kernel_launch(void* const* d_in, const int* in_sizes, int n_in,
                              void* d_out, int out_size, void* d_ws, size_t ws_size,
                              hipStream_t stream) {
  (void)in_sizes; (void)n_in; (void)d_ws; (void)ws_size;
  const float* V = (const float*)d_in[0];
  const float* Pre = (const float*)d_in[1];
  const float* Pim = (const float*)d_in[2];
  const int* pos = (const int*)d_in[3];
  float* out = (float*)d_out;
  const int n = out_size;  // 256*128*128
  const int n4 = n >> 2;
  zero_k<<<dim3((n4 + 255) / 256), dim3(256), 0, stream>>>((float4*)out, n4);
  msp_mode<<<dim3(1024), dim3(512), 0, stream>>>(V, Pre, Pim, pos, out);
  sqrt_k<<<dim3((n + 255) / 256), dim3(256), 0, stream>>>(out, n);
}

// Round 9
// 949.767 us; speedup vs baseline: 2.3726x; 2.1261x over previous
//
#include <hip/hip_runtime.h>
#include <math.h>

namespace {

constexpr int TNZ = 8, TNY = 512, TNX = 512, TM = 128;
constexpr int PITCH = 130;                 // float2 pitch of LDS field
constexpr float F0 = 1.0f / (TM * 0.2f);   // fftfreq step 1/(M*dr)
constexpr float PK = -3.14159265358979323846f * 0.025f * 10.0f;  // -pi*lambda*dz
constexpr float INV_N2 = 1.0f / (TM * TM);
constexpr float EPSV = 1e-10f;

__device__ __forceinline__ float2 cmul(float2 a, float2 b) {
  return make_float2(a.x * b.x - a.y * b.y, a.x * b.y + a.y * b.x);
}
__device__ __forceinline__ float2 cmulc(float2 a, float2 b) {  // a * conj(b)
  return make_float2(a.x * b.x + a.y * b.y, a.y * b.x - a.x * b.y);
}
__device__ __forceinline__ float2 shxor(float2 v, int m) {
  return make_float2(__shfl_xor(v.x, m, 64), __shfl_xor(v.y, m, 64));
}
__device__ __forceinline__ int rev7(int n) {
  return ((n & 1) << 6) | ((n & 2) << 4) | ((n & 4) << 2) | (n & 8) |
         ((n & 16) >> 2) | ((n & 32) >> 4) | ((n & 64) >> 6);
}
__device__ __forceinline__ int opq(int v) {  // defeat cross-iteration CSE/LICM
  asm volatile("" : "+v"(v));
  return v;
}
// Unified storage swizzle: element (y,x) lives at fld[y*PITCH + slot(y,x)].
// Folds x's segment bits (4-6 -> 0-2) and y's group bits (4-6 -> 1-3):
// row reads (x=16s'+j varies, y/wave 8 consecutive) and col reads
// (y=16s+j varies, x/wave 8 consecutive) both land on the b64 bank floor
// (4 lanes per bank-pair) -- verified by bank arithmetic.
__device__ __forceinline__ int slotf(int y, int x) {
  return x ^ ((x & 0x70) >> 4) ^ ((y & 0x70) >> 3);
}

// ---- local (in-thread) radix-2 stages over 16 elements ----
// twd[m] = exp(-2*pi*i*m/128), m < 64
template <int H>
__device__ __forceinline__ void dif_local(float2 (&X)[16], const float2* twd,
                                          int toff) {
#pragma unroll
  for (int m = 0; m < H; ++m) {
    float2 W = twd[toff + m * (64 / H)];
#pragma unroll
    for (int b = 0; b < 16; b += 2 * H) {
      const int j = b + m;
      float2 A = X[j], B = X[j + H];
      X[j] = make_float2(A.x + B.x, A.y + B.y);
      float2 d = make_float2(A.x - B.x, A.y - B.y);
      X[j + H] = cmul(d, W);
    }
  }
}
template <int H>
__device__ __forceinline__ void dit_local(float2 (&X)[16], const float2* twd,
                                          int toff) {
#pragma unroll
  for (int m = 0; m < H; ++m) {
    float2 W = twd[toff + m * (64 / H)];
#pragma unroll
    for (int b = 0; b < 16; b += 2 * H) {
      const int j = b + m;
      float2 A = X[j];
      float2 B = cmulc(X[j + H], W);
      X[j] = make_float2(A.x + B.x, A.y + B.y);
      X[j + H] = make_float2(A.x - B.x, A.y - B.y);
    }
  }
}

// Forward DIF FFT-128; segment s (0..7) owns n = 16*s + j. Natural in,
// bit-reversed positions out. (Validated 8-segment core from R2.)
__device__ __forceinline__ void dif128(float2 (&X)[16], const float2* twd,
                                       const float2* twdp, int s, int toff) {
  const bool b4 = (s & 4) != 0, b2 = (s & 2) != 0, b1 = (s & 1) != 0;
#pragma unroll
  for (int j = 0; j < 16; ++j) {  // h=64, partner ^4 ; W = W128^{16(s&3)+j}
    float2 o = shxor(X[j], 4);
    float2 W = twdp[toff + (s & 3) * 17 + j];
    float2 sum = make_float2(X[j].x + o.x, X[j].y + o.y);
    float2 dif = make_float2(o.x - X[j].x, o.y - X[j].y);
    float2 pr = cmul(dif, W);
    X[j] = b4 ? pr : sum;
  }
#pragma unroll
  for (int j = 0; j < 16; ++j) {  // h=32, partner ^2 ; W = twd[32(s&1)+2j]
    float2 o = shxor(X[j], 2);
    float2 W = twd[toff + 32 * (s & 1) + 2 * j];
    float2 sum = make_float2(X[j].x + o.x, X[j].y + o.y);
    float2 dif = make_float2(o.x - X[j].x, o.y - X[j].y);
    float2 pr = cmul(dif, W);
    X[j] = b2 ? pr : sum;
  }
#pragma unroll
  for (int j = 0; j < 16; ++j) {  // h=16, partner ^1 ; W = twd[4j]
    float2 o = shxor(X[j], 1);
    float2 W = twd[toff + 4 * j];
    float2 sum = make_float2(X[j].x + o.x, X[j].y + o.y);
    float2 dif = make_float2(o.x - X[j].x, o.y - X[j].y);
    float2 pr = cmul(dif, W);
    X[j] = b1 ? pr : sum;
  }
  dif_local<8>(X, twd, toff);
  dif_local<4>(X, twd, toff);
  dif_local<2>(X, twd, toff);
#pragma unroll
  for (int b = 0; b < 16; b += 2) {  // h=1, W=1
    float2 A = X[b], B = X[b + 1];
    X[b] = make_float2(A.x + B.x, A.y + B.y);
    X[b + 1] = make_float2(A.x - B.x, A.y - B.y);
  }
}

// Inverse (DIT) FFT-128: exact inverse network (bitrev in, natural out, unscaled)
__device__ __forceinline__ void dit128(float2 (&X)[16], const float2* twd,
                                       const float2* twdp, int s, int toff) {
  const bool b4 = (s & 4) != 0, b2 = (s & 2) != 0, b1 = (s & 1) != 0;
#pragma unroll
  for (int b = 0; b < 16; b += 2) {  // h=1
    float2 A = X[b], B = X[b + 1];
    X[b] = make_float2(A.x + B.x, A.y + B.y);
    X[b + 1] = make_float2(A.x - B.x, A.y - B.y);
  }
  dit_local<2>(X, twd, toff);
  dit_local<4>(X, twd, toff);
  dit_local<8>(X, twd, toff);
  {  // cross h=16, partner ^1 : W = twd[4j]
    const float sg = b1 ? -1.0f : 1.0f;
#pragma unroll
    for (int j = 0; j < 16; ++j) {
      float2 o = shxor(X[j], 1);
      float2 W = twd[toff + 4 * j];
      float2 vin = b1 ? X[j] : o;
      float2 u = b1 ? o : X[j];
      float2 B = cmulc(vin, W);
      X[j] = make_float2(fmaf(sg, B.x, u.x), fmaf(sg, B.y, u.y));
    }
  }
  {  // cross h=32, partner ^2 : W = twd[32(s&1)+2j]
    const float sg = b2 ? -1.0f : 1.0f;
#pragma unroll
    for (int j = 0; j < 16; ++j) {
      float2 o = shxor(X[j], 2);
      float2 W = twd[toff + 32 * (s & 1) + 2 * j];
      float2 vin = b2 ? X[j] : o;
      float2 u = b2 ? o : X[j];
      float2 B = cmulc(vin, W);
      X[j] = make_float2(fmaf(sg, B.x, u.x), fmaf(sg, B.y, u.y));
    }
  }
  {  // cross h=64, partner ^4 : W = twdp[(s&3)*17+j]
    const float sg = b4 ? -1.0f : 1.0f;
#pragma unroll
    for (int j = 0; j < 16; ++j) {
      float2 o = shxor(X[j], 4);
      float2 W = twdp[toff + (s & 3) * 17 + j];
      float2 vin = b4 ? X[j] : o;
      float2 u = b4 ? o : X[j];
      float2 B = cmulc(vin, W);
      X[j] = make_float2(fmaf(sg, B.x, u.x), fmaf(sg, B.y, u.y));
    }
  }
}

// Phase R: per half (64 rows): [rowI] -> T(z)-multiply -> rowF, field in LDS
__device__ __forceinline__ void phaseR(float2* fld, const float2* twd,
                                       const float2* twdp, const float* V,
                                       int z, int p0, int p1, int s, int g,
                                       bool doInv) {
#pragma unroll
  for (int h = 0; h < 2; ++h) {
    const int toff = opq(0);
    const int y = g + 64 * h;
    const int swzk = (y & 0x70) >> 3;
    float2 X[16];
#pragma unroll
    for (int j = 0; j < 16; ++j)
      X[j] = fld[y * PITCH + ((16 * s + j) ^ s ^ swzk)];
    if (doInv) dit128(X, twd, twdp, s, toff);
    const float* vb = V + ((z * TNY + (p0 + y)) * TNX + p1 + 16 * s);
#pragma unroll
    for (int j = 0; j < 16; ++j) {
      float v = vb[j];
      float sv, cv;
      __sincosf(v, &sv, &cv);
      X[j] = cmul(X[j], make_float2(cv, sv));
    }
    dif128(X, twd, twdp, s, toff);
#pragma unroll
    for (int j = 0; j < 16; ++j)
      fld[y * PITCH + ((16 * s + j) ^ s ^ swzk)] = X[j];
  }
}

// Phase C: per half (64 cols): colF -> [H -> colI] or [|.|^2 write-back]
template <bool LAST>
__device__ __forceinline__ void phaseC(float2* fld, const float2* twd,
                                       const float2* twdp, const float2* hyp,
                                       int s, int g) {
#pragma unroll
  for (int h = 0; h < 2; ++h) {
    const int toff = opq(0);
    const int c = g + 64 * h;
    const int slotc = (c ^ ((c & 0x70) >> 4)) ^ (2 * s);  // (y&0x70)>>3 = 2s
    float2 X[16];
#pragma unroll
    for (int j = 0; j < 16; ++j) X[j] = fld[(16 * s + j) * PITCH + slotc];
    dif128(X, twd, twdp, s, toff);
    if constexpr (!LAST) {
      const int kx = rev7(c);
      const int ixf = kx - ((kx & 64) ? 128 : 0);
      float sp, cp;
      __sincosf(PK * (ixf * F0) * (ixf * F0), &sp, &cp);
      const float2 hxv = make_float2(cp * INV_N2, sp * INV_N2);
#pragma unroll
      for (int j = 0; j < 16; ++j) {
        float2 hy = hyp[toff + s * 17 + j];
        X[j] = cmul(cmul(X[j], hy), hxv);
      }
      dit128(X, twd, twdp, s, toff);
#pragma unroll
      for (int j = 0; j < 16; ++j) fld[(16 * s + j) * PITCH + slotc] = X[j];
    } else {
      // |psi_f|^2, written back to the SAME slots this thread read (no race)
#pragma unroll
      for (int j = 0; j < 16; ++j) {
        float v = fmaf(X[j].x, X[j].x, X[j].y * X[j].y);
        fld[(16 * s + j) * PITCH + slotc] = make_float2(v, v);
      }
    }
  }
}

// One block = one (k, mode). Accumulates |psi_f|^2 into out via atomicAdd.
__global__ __launch_bounds__(512, 1)
void msp_mode(const float* __restrict__ V, const float* __restrict__ Pre,
              const float* __restrict__ Pim, const int* __restrict__ pos,
              float* __restrict__ out) {
  __shared__ float2 fld[TM * PITCH];  // 133,120 B field buffer
  __shared__ float2 twd[64];
  __shared__ float2 twdp[4 * 17];  // W128^{16q+j} at [q*17+j] (padded)
  __shared__ float2 hyp[8 * 17];   // hy for storage y=16s+j at [s*17+j]

  const int t = threadIdx.x;
  const int k = blockIdx.x >> 2;
  const int m = blockIdx.x & 3;
  const int s = t & 7;    // segment within a row/col (owns 16 elements)
  const int g = t >> 3;   // row (phase R) / col (phase C) group, 0..63

  if (t < 64) {
    float ang = -6.28318530717958647692f * (float)t / 128.0f;
    float2 w = make_float2(cosf(ang), sinf(ang));
    twd[t] = w;
    twdp[(t >> 4) * 17 + (t & 15)] = w;  // W128^t at q=t>>4, j=t&15
  }
  if (t < 128) {
    const int ky = rev7(t);
    const int iy = ky - ((ky & 64) ? 128 : 0);
    const float fy = iy * F0;
    const float ph = PK * fy * fy;
    hyp[(t >> 4) * 17 + (t & 15)] = make_float2(cosf(ph), sinf(ph));
  }

  // load probe mode m into the LDS field (swizzled storage)
#pragma unroll
  for (int h = 0; h < 2; ++h) {
    const int y = g + 64 * h;
    const int swzk = (y & 0x70) >> 3;
    const float4* pr =
        reinterpret_cast<const float4*>(Pre + (m * TM + y) * TM + 16 * s);
    const float4* pi =
        reinterpret_cast<const float4*>(Pim + (m * TM + y) * TM + 16 * s);
#pragma unroll
    for (int q = 0; q < 4; ++q) {
      float4 a = pr[q], b = pi[q];
      const int x0 = 16 * s + 4 * q;
      fld[y * PITCH + ((x0 + 0) ^ s ^ swzk)] = make_float2(a.x, b.x);
      fld[y * PITCH + ((x0 + 1) ^ s ^ swzk)] = make_float2(a.y, b.y);
      fld[y * PITCH + ((x0 + 2) ^ s ^ swzk)] = make_float2(a.z, b.z);
      fld[y * PITCH + ((x0 + 3) ^ s ^ swzk)] = make_float2(a.w, b.w);
    }
  }
  __syncthreads();

  const int p0 = pos[2 * k];
  const int p1 = pos[2 * k + 1];

#pragma unroll 1
  for (int z = 0; z < TNZ; ++z) {
    phaseR(fld, twd, twdp, V, z, p0, p1, s, g, z > 0);
    __syncthreads();
    if (z < TNZ - 1) {
      phaseC<false>(fld, twd, twdp, hyp, s, g);
      __syncthreads();
    }
  }
  phaseC<true>(fld, twd, twdp, hyp, s, g);
  __syncthreads();

  // gather (un-swizzle + un-bit-reverse) and coalesced atomic accumulate
  float* ob = out + k * (TM * TM);
#pragma unroll
  for (int i = 0; i < 32; ++i) {
    const int idx = t + 512 * i;
    const int ky = idx >> 7, kx = idx & 127;
    const int y = rev7(ky), c = rev7(kx);
    atomicAdd(&ob[idx], fld[y * PITCH + slotf(y, c)].x);
  }
}

__global__ __launch_bounds__(256) void zero_k(float4* __restrict__ p, int n4) {
  const int i = blockIdx.x * 256 + threadIdx.x;
  if (i < n4) p[i] = make_float4(0.f, 0.f, 0.f, 0.f);
}

__global__ __launch_bounds__(256) void sqrt_k(float* __restrict__ p, int n) {
  const int i = blockIdx.x * 256 + threadIdx.x;
  if (i < n) p[i] = sqrtf(EPSV + p[i] * INV_N2);  // ortho: 1/N^2 on |.|^2
}

}  // namespace

extern "C" void kernel_launch(void* const* d_in, const int* in_sizes, int n_in,
                              void* d_out, int out_size, void* d_ws, size_t ws_size,
                              hipStream_t stream) {
  (void)in_sizes; (void)n_in; (void)d_ws; (void)ws_size;
  const float* V = (const float*)d_in[0];
  const float* Pre = (const float*)d_in[1];
  const float* Pim = (const float*)d_in[2];
  const int* pos = (const int*)d_in[3];
  float* out = (float*)d_out;
  const int n = out_size;  // 256*128*128
  const int n4 = n >> 2;
  zero_k<<<dim3((n4 + 255) / 256), dim3(256), 0, stream>>>((float4*)out, n4);
  msp_mode<<<dim3(1024), dim3(512), 0, stream>>>(V, Pre, Pim, pos, out);
  sqrt_k<<<dim3((n + 255) / 256), dim3(256), 0, stream>>>(out, n);
}

// Round 10
// 923.486 us; speedup vs baseline: 2.4402x; 1.0285x over previous
//
#include <hip/hip_runtime.h>
#include <math.h>

namespace {

constexpr int TNZ = 8, TNY = 512, TNX = 512, TM = 128;
constexpr int PITCH = 130;                 // float2 pitch of LDS field
constexpr float F0 = 1.0f / (TM * 0.2f);   // fftfreq step 1/(M*dr)
constexpr float PK = -3.14159265358979323846f * 0.025f * 10.0f;  // -pi*lambda*dz
constexpr float PKF = PK * F0 * F0;        // phase = PKF * (iy^2 + ix^2)
constexpr float INV_N2 = 1.0f / (TM * TM);
constexpr float EPSV = 1e-10f;
constexpr float PIF = 3.14159265358979323846f;

// ---- compile-time scalar twiddles (double Taylor, exact to fp32).
// SCALAR static-constexpr members only: no arrays -> no .rodata loads; the
// values become instruction-stream / SGPR literals.
constexpr double PI_D = 3.14159265358979323846264338327950288;
constexpr double tsin(double x) {
  double t = x, s = x, x2 = x * x;
  for (int n = 1; n <= 24; ++n) { t *= -x2 / double((2 * n) * (2 * n + 1)); s += t; }
  return s;
}
constexpr double tcos(double x) {
  double t = 1.0, s = 1.0, x2 = x * x;
  for (int n = 1; n <= 24; ++n) { t *= -x2 / double((2 * n - 1) * (2 * n)); s += t; }
  return s;
}
template <int K, int N> struct Wc {  // exp(-2*pi*i*K/N)
  static constexpr float re = (float)tcos(-2.0 * PI_D * (double)K / (double)N);
  static constexpr float im = (float)tsin(-2.0 * PI_D * (double)K / (double)N);
};

// compile-time-index unroll helper
template <int I> struct Ic { static constexpr int v = I; };
template <int I, int N, typename F>
__device__ __forceinline__ void u_impl(F&& f) {
  if constexpr (I < N) { f(Ic<I>{}); u_impl<I + 1, N>(f); }
}
template <int N, typename F>
__device__ __forceinline__ void u_for(F&& f) { u_impl<0, N>(f); }

__device__ __forceinline__ float2 cmul(float2 a, float2 b) {
  return make_float2(a.x * b.x - a.y * b.y, a.x * b.y + a.y * b.x);
}
__device__ __forceinline__ float2 cmulc(float2 a, float2 b) {  // a * conj(b)
  return make_float2(a.x * b.x + a.y * b.y, a.y * b.x - a.x * b.y);
}
__device__ __forceinline__ float2 shxor(float2 v, int m) {
  return make_float2(__shfl_xor(v.x, m, 64), __shfl_xor(v.y, m, 64));
}
__device__ __forceinline__ int rev7(int n) {
  return ((n & 1) << 6) | ((n & 2) << 4) | ((n & 4) << 2) | (n & 8) |
         ((n & 16) >> 2) | ((n & 32) >> 4) | ((n & 64) >> 6);
}
constexpr int crev3(int i) { return ((i & 1) << 2) | (i & 2) | ((i & 4) >> 2); }
// Storage swizzle: element (y,x) at fld[y*PITCH + slot(y,x)].
// Folds bits 3-6 of x and of y into the low 4 bits; verified by bank
// arithmetic that row-pass (x=8q+m, q varies per lane) and col-pass
// (y=8q+i) b64 accesses are both uniform 4 dwords/bank (the floor).
__device__ __forceinline__ int slotf(int y, int x) {
  return x ^ ((x & 0x78) >> 3) ^ ((y & 0x78) >> 3);
}

// ---- FFT-128, ownership p = 8q + i (q = lane&15, i = 0..7 in registers) ----
// Cross stages (h=64,32,16,8) via shfl masks 8,4,2,1; locals h=4,2,1.
// Twiddles: W_stage = rq * Wc<i,*> with rq64 = W128^{8(q&7)}, rq32 = W64^{8(q&3)},
// rq16 = (q&1 ? -i : 1) folded as a component swap. DIF: natural in, bitrev out.
__device__ __forceinline__ void dif8(float2 (&X)[8], int q, float2 rq64,
                                     float2 rq32) {
  const bool u8 = (q & 8) != 0, u4 = (q & 4) != 0, u2 = (q & 2) != 0,
             u1 = (q & 1) != 0;
  u_for<8>([&](auto I) {  // h=64, mask 8: W = rq64 * W128^i
    constexpr int i = I.v;
    float2 o = shxor(X[i], 8);
    float2 s = make_float2(X[i].x + o.x, X[i].y + o.y);
    float2 d = make_float2(o.x - X[i].x, o.y - X[i].y);
    float2 pr = cmul(cmul(d, rq64), make_float2(Wc<i, 128>::re, Wc<i, 128>::im));
    X[i] = u8 ? pr : s;
  });
  u_for<8>([&](auto I) {  // h=32, mask 4: W = rq32 * W64^i
    constexpr int i = I.v;
    float2 o = shxor(X[i], 4);
    float2 s = make_float2(X[i].x + o.x, X[i].y + o.y);
    float2 d = make_float2(o.x - X[i].x, o.y - X[i].y);
    float2 pr = cmul(cmul(d, rq32), make_float2(Wc<i, 64>::re, Wc<i, 64>::im));
    X[i] = u4 ? pr : s;
  });
  u_for<8>([&](auto I) {  // h=16, mask 2: W = (q&1 ? -i : 1) * W32^i
    constexpr int i = I.v;
    float2 o = shxor(X[i], 2);
    float2 s = make_float2(X[i].x + o.x, X[i].y + o.y);
    float2 d = make_float2(o.x - X[i].x, o.y - X[i].y);
    float2 t = cmul(d, make_float2(Wc<i, 32>::re, Wc<i, 32>::im));
    float2 pr = u1 ? make_float2(t.y, -t.x) : t;
    X[i] = u2 ? pr : s;
  });
  u_for<8>([&](auto I) {  // h=8, mask 1: W = W16^i (pure literal)
    constexpr int i = I.v;
    float2 o = shxor(X[i], 1);
    float2 s = make_float2(X[i].x + o.x, X[i].y + o.y);
    float2 d = make_float2(o.x - X[i].x, o.y - X[i].y);
    float2 pr = cmul(d, make_float2(Wc<i, 16>::re, Wc<i, 16>::im));
    X[i] = u1 ? pr : s;
  });
  u_for<4>([&](auto I) {  // h=4 local: W = W8^i
    constexpr int i = I.v;
    float2 A = X[i], B = X[i + 4];
    X[i] = make_float2(A.x + B.x, A.y + B.y);
    float2 d = make_float2(A.x - B.x, A.y - B.y);
    X[i + 4] = cmul(d, make_float2(Wc<i, 8>::re, Wc<i, 8>::im));
  });
  u_for<4>([&](auto I) {  // h=2 local: lower idx in {0,1,4,5}; W = (g&1 ? -i : 1)
    constexpr int g = (I.v >> 1) * 4 + (I.v & 1);
    float2 A = X[g], B = X[g + 2];
    X[g] = make_float2(A.x + B.x, A.y + B.y);
    float2 d = make_float2(A.x - B.x, A.y - B.y);
    X[g + 2] = (g & 1) ? make_float2(d.y, -d.x) : d;
  });
  u_for<4>([&](auto I) {  // h=1 local: W = 1
    constexpr int e = I.v * 2;
    float2 A = X[e], B = X[e + 1];
    X[e] = make_float2(A.x + B.x, A.y + B.y);
    X[e + 1] = make_float2(A.x - B.x, A.y - B.y);
  });
}

// Inverse: exact mirror network, conj twiddles (bitrev in, natural out, unscaled)
__device__ __forceinline__ void dit8(float2 (&X)[8], int q, float2 rq64,
                                     float2 rq32) {
  const bool u8 = (q & 8) != 0, u4 = (q & 4) != 0, u2 = (q & 2) != 0,
             u1 = (q & 1) != 0;
  u_for<4>([&](auto I) {  // h=1
    constexpr int e = I.v * 2;
    float2 A = X[e], B = X[e + 1];
    X[e] = make_float2(A.x + B.x, A.y + B.y);
    X[e + 1] = make_float2(A.x - B.x, A.y - B.y);
  });
  u_for<4>([&](auto I) {  // h=2: B = v * conj(W4^{g&1})
    constexpr int g = (I.v >> 1) * 4 + (I.v & 1);
    float2 A = X[g], v = X[g + 2];
    float2 B = (g & 1) ? make_float2(-v.y, v.x) : v;  // v * (+i)
    X[g] = make_float2(A.x + B.x, A.y + B.y);
    X[g + 2] = make_float2(A.x - B.x, A.y - B.y);
  });
  u_for<4>([&](auto I) {  // h=4: B = v * conj(W8^i)
    constexpr int i = I.v;
    float2 A = X[i];
    float2 B = cmulc(X[i + 4], make_float2(Wc<i, 8>::re, Wc<i, 8>::im));
    X[i] = make_float2(A.x + B.x, A.y + B.y);
    X[i + 4] = make_float2(A.x - B.x, A.y - B.y);
  });
  u_for<8>([&](auto I) {  // h=8, mask 1: conj(W16^i)
    constexpr int i = I.v;
    float2 o = shxor(X[i], 1);
    float2 vv = u1 ? X[i] : o;
    float2 uu = u1 ? o : X[i];
    float2 B = cmulc(vv, make_float2(Wc<i, 16>::re, Wc<i, 16>::im));
    const float sg = u1 ? -1.0f : 1.0f;
    X[i] = make_float2(fmaf(sg, B.x, uu.x), fmaf(sg, B.y, uu.y));
  });
  u_for<8>([&](auto I) {  // h=16, mask 2: conj((q&1?-i:1) * W32^i)
    constexpr int i = I.v;
    float2 o = shxor(X[i], 2);
    float2 vv = u2 ? X[i] : o;
    float2 uu = u2 ? o : X[i];
    float2 B = cmulc(vv, make_float2(Wc<i, 32>::re, Wc<i, 32>::im));
    B = u1 ? make_float2(-B.y, B.x) : B;  // * conj(-i) = * (+i)
    const float sg = u2 ? -1.0f : 1.0f;
    X[i] = make_float2(fmaf(sg, B.x, uu.x), fmaf(sg, B.y, uu.y));
  });
  u_for<8>([&](auto I) {  // h=32, mask 4: conj(rq32 * W64^i)
    constexpr int i = I.v;
    float2 o = shxor(X[i], 4);
    float2 vv = u4 ? X[i] : o;
    float2 uu = u4 ? o : X[i];
    float2 B = cmulc(cmulc(vv, make_float2(Wc<i, 64>::re, Wc<i, 64>::im)), rq32);
    const float sg = u4 ? -1.0f : 1.0f;
    X[i] = make_float2(fmaf(sg, B.x, uu.x), fmaf(sg, B.y, uu.y));
  });
  u_for<8>([&](auto I) {  // h=64, mask 8: conj(rq64 * W128^i)
    constexpr int i = I.v;
    float2 o = shxor(X[i], 8);
    float2 vv = u8 ? X[i] : o;
    float2 uu = u8 ? o : X[i];
    float2 B = cmulc(cmulc(vv, make_float2(Wc<i, 128>::re, Wc<i, 128>::im)), rq64);
    const float sg = u8 ? -1.0f : 1.0f;
    X[i] = make_float2(fmaf(sg, B.x, uu.x), fmaf(sg, B.y, uu.y));
  });
}

// One block = one (k, mode). 1024 threads: q = t&15 (segment), gg = t>>4.
__global__ __launch_bounds__(1024)
void msp_mode(const float* __restrict__ V, const float* __restrict__ Pre,
              const float* __restrict__ Pim, const int* __restrict__ pos,
              float* __restrict__ out) {
  __shared__ float2 fld[TM * PITCH];  // 133,120 B field buffer

  const int t = threadIdx.x;
  const int k = blockIdx.x >> 2;
  const int m = blockIdx.x & 3;
  const int q = t & 15;   // segment within a row/col (owns 8 consecutive)
  const int gg = t >> 4;  // row (phase R) / col (phase C) group, 0..63

  // per-thread twiddle constants
  float sc, cc0;
  __sincosf(-PIF * (float)(q & 7) * 0.125f, &sc, &cc0);
  const float2 rq64 = make_float2(cc0, sc);  // W128^{8(q&7)}
  __sincosf(-PIF * (float)(q & 3) * 0.25f, &sc, &cc0);
  const float2 rq32 = make_float2(cc0, sc);  // W64^{8(q&3)}
  const int rev4q =
      ((q & 1) << 3) | ((q & 2) << 1) | ((q & 4) >> 1) | ((q & 8) >> 3);

  const int p0 = pos[2 * k];
  const int p1 = pos[2 * k + 1];

  // load probe mode m into the LDS field (swizzled storage)
#pragma unroll 1
  for (int h = 0; h < 2; ++h) {
    const int y = gg + 64 * h;
    const int S = (8 * q) ^ q ^ ((y & 0x78) >> 3);
    const float4* pr =
        reinterpret_cast<const float4*>(Pre + (m * TM + y) * TM + 8 * q);
    const float4* pi =
        reinterpret_cast<const float4*>(Pim + (m * TM + y) * TM + 8 * q);
    u_for<2>([&](auto Q) {
      constexpr int qq = Q.v;
      float4 a = pr[qq], b = pi[qq];
      fld[y * PITCH + (S ^ (4 * qq + 0))] = make_float2(a.x, b.x);
      fld[y * PITCH + (S ^ (4 * qq + 1))] = make_float2(a.y, b.y);
      fld[y * PITCH + (S ^ (4 * qq + 2))] = make_float2(a.z, b.z);
      fld[y * PITCH + (S ^ (4 * qq + 3))] = make_float2(a.w, b.w);
    });
  }
  __syncthreads();

#pragma unroll 1
  for (int z = 0; z < TNZ; ++z) {
    // phase R: [rowI if z>0] -> T(z) -> rowF, per half
#pragma unroll 1
    for (int h = 0; h < 2; ++h) {
      const int y = gg + 64 * h;
      const int S = (8 * q) ^ q ^ ((y & 0x78) >> 3);
      float2 X[8];
      u_for<8>([&](auto I) { X[I.v] = fld[y * PITCH + (S ^ I.v)]; });
      if (z > 0) dit8(X, q, rq64, rq32);
      const float* vb = V + (((z * TNY) + (p0 + y)) * TNX + p1 + 8 * q);
      u_for<8>([&](auto I) {
        constexpr int i = I.v;
        float v = vb[i];
        float sv, cv;
        __sincosf(v, &sv, &cv);
        X[i] = cmul(X[i], make_float2(cv, sv));
      });
      dif8(X, q, rq64, rq32);
      u_for<8>([&](auto I) { fld[y * PITCH + (S ^ I.v)] = X[I.v]; });
    }
    __syncthreads();

    // phase C: colF -> [H -> colI] (or |.|^2 on the last slice)
    const bool last = (z == TNZ - 1);
#pragma unroll 1
    for (int h = 0; h < 2; ++h) {
      const int c = gg + 64 * h;
      const int slotc = c ^ ((c & 0x78) >> 3) ^ q;  // slot(8q+i, c), i<8
      float2 X[8];
      u_for<8>([&](auto I) { X[I.v] = fld[(8 * q + I.v) * PITCH + slotc]; });
      dif8(X, q, rq64, rq32);
      if (!last) {
        const int kx = rev7(c);
        const int ixf = kx - ((kx & 64) ? 128 : 0);
        const float fx2 = (float)(ixf * ixf);
        u_for<8>([&](auto I) {  // H at ky = 16*rev3(i) + rev4(q); 1/N^2 folded
          constexpr int i = I.v;
          const int ky = 16 * crev3(i) + rev4q;
          const int iy = ky - ((i & 1) ? 128 : 0);
          float sp, cp;
          __sincosf(PKF * ((float)(iy * iy) + fx2), &sp, &cp);
          X[i] = cmul(X[i], make_float2(cp * INV_N2, sp * INV_N2));
        });
        dit8(X, q, rq64, rq32);
        u_for<8>([&](auto I) { fld[(8 * q + I.v) * PITCH + slotc] = X[I.v]; });
      } else {
        u_for<8>([&](auto I) {  // |psi_f|^2 back to the same slots (no race)
          constexpr int i = I.v;
          float v = fmaf(X[i].x, X[i].x, X[i].y * X[i].y);
          fld[(8 * q + i) * PITCH + slotc] = make_float2(v, v);
        });
      }
    }
    __syncthreads();
  }

  // gather (un-swizzle + un-bit-reverse) and coalesced atomic accumulate
  float* ob = out + k * (TM * TM);
#pragma unroll
  for (int ii = 0; ii < 16; ++ii) {
    const int idx = t + 1024 * ii;
    const int ky = idx >> 7, kx = idx & 127;
    const int y = rev7(ky), x = rev7(kx);
    atomicAdd(&ob[idx], fld[y * PITCH + slotf(y, x)].x);
  }
}

__global__ __launch_bounds__(256) void zero_k(float4* __restrict__ p, int n4) {
  const int i = blockIdx.x * 256 + threadIdx.x;
  if (i < n4) p[i] = make_float4(0.f, 0.f, 0.f, 0.f);
}

__global__ __launch_bounds__(256) void sqrt_k(float* __restrict__ p, int n) {
  const int i = blockIdx.x * 256 + threadIdx.x;
  if (i < n) p[i] = sqrtf(EPSV + p[i] * INV_N2);  // ortho: 1/N^2 on |.|^2
}

}  // namespace

extern "C" void kernel_launch(void* const* d_in, const int* in_sizes, int n_in,
                              void* d_out, int out_size, void* d_ws, size_t ws_size,
                              hipStream_t stream) {
  (void)in_sizes; (void)n_in; (void)d_ws; (void)ws_size;
  const float* V = (const float*)d_in[0];
  const float* Pre = (const float*)d_in[1];
  const float* Pim = (const float*)d_in[2];
  const int* pos = (const int*)d_in[3];
  float* out = (float*)d_out;
  const int n = out_size;  // 256*128*128
  const int n4 = n >> 2;
  zero_k<<<dim3((n4 + 255) / 256), dim3(256), 0, stream>>>((float4*)out, n4);
  msp_mode<<<dim3(1024), dim3(1024), 0, stream>>>(V, Pre, Pim, pos, out);
  sqrt_k<<<dim3((n + 255) / 256), dim3(256), 0, stream>>>(out, n);
}

// Round 11
// 835.314 us; speedup vs baseline: 2.6977x; 1.1056x over previous
//
#include <hip/hip_runtime.h>
#include <math.h>

namespace {

constexpr int TNZ = 8, TNY = 512, TNX = 512, TM = 128;
constexpr int PITCH = 130;  // float2 pitch; 130 % 16 == 2 rotates banks naturally
constexpr float F0 = 1.0f / (TM * 0.2f);
constexpr float PK = -3.14159265358979323846f * 0.025f * 10.0f;
constexpr float PKF = PK * F0 * F0;  // phase = PKF * (iy^2 + ix^2)
constexpr float INV_N2 = 1.0f / (TM * TM);
constexpr float EPSV = 1e-10f;
constexpr float PIF = 3.14159265358979323846f;
constexpr float RT2H = 0.70710678118654752440f;

// compile-time-index unroll helper
template <int I> struct Ic { static constexpr int v = I; };
template <int I, int N, typename F>
__device__ __forceinline__ void u_impl(F&& f) {
  if constexpr (I < N) { f(Ic<I>{}); u_impl<I + 1, N>(f); }
}
template <int N, typename F>
__device__ __forceinline__ void u_for(F&& f) { u_impl<0, N>(f); }

__device__ __forceinline__ float2 cmul(float2 a, float2 b) {
  return make_float2(a.x * b.x - a.y * b.y, a.x * b.y + a.y * b.x);
}
__device__ __forceinline__ float2 cmulc(float2 a, float2 b) {  // a * conj(b)
  return make_float2(a.x * b.x + a.y * b.y, a.y * b.x - a.x * b.y);
}
__device__ __forceinline__ float2 shxor(float2 v, int m) {
  return make_float2(__shfl_xor(v.x, m, 64), __shfl_xor(v.y, m, 64));
}
__device__ __forceinline__ float2 fma2(float sg, float2 mine, float2 oth) {
  return make_float2(fmaf(sg, mine.x, oth.x), fmaf(sg, mine.y, oth.y));
}
__device__ __forceinline__ int rev7(int n) {
  return ((n & 1) << 6) | ((n & 2) << 4) | ((n & 4) << 2) | (n & 8) |
         ((n & 16) >> 2) | ((n & 32) >> 4) | ((n & 64) >> 6);
}
constexpr int crev3(int i) { return ((i & 1) << 2) | (i & 2) | ((i & 4) >> 2); }

// multiply by W8^i (literal): W8 = exp(-i*pi/4)
template <int i> __device__ __forceinline__ float2 mulW8(float2 t) {
  if constexpr (i == 0) return t;
  else if constexpr (i == 1)
    return make_float2(RT2H * (t.x + t.y), RT2H * (t.y - t.x));
  else if constexpr (i == 2) return make_float2(t.y, -t.x);
  else return make_float2(RT2H * (t.y - t.x), -RT2H * (t.x + t.y));
}
// multiply by conj(W8^i)
template <int i> __device__ __forceinline__ float2 mulW8c(float2 t) {
  if constexpr (i == 0) return t;
  else if constexpr (i == 1)
    return make_float2(RT2H * (t.x - t.y), RT2H * (t.x + t.y));
  else if constexpr (i == 2) return make_float2(-t.y, t.x);
  else return make_float2(-RT2H * (t.x + t.y), RT2H * (t.x - t.y));
}

struct Tw8 {
  float2 wq128, wq64, wq32;  // W128^q, W64^q, W32^q
  float2 ws8, ws4, ws2;      // upper-lane stage twiddles (lower lanes: 1)
  float sg8, sg4, sg2, sg1;  // butterfly signs per lane
};

// ---- FFT-128, ownership p = q + 16*i (q = lane&15, i = reg 0..7) ----
// DIF forward: natural position order in, bit-reversed order out.
__device__ __forceinline__ void dif8(float2 (&X)[8], const Tw8& T) {
  u_for<4>([&](auto I) {  // h=64 local: pairs (i, i+4); W = wq128 * W8^i
    constexpr int i = I.v;
    float2 A = X[i], B = X[i + 4];
    X[i] = make_float2(A.x + B.x, A.y + B.y);
    float2 d = make_float2(A.x - B.x, A.y - B.y);
    X[i + 4] = mulW8<i>(cmul(d, T.wq128));
  });
  u_for<4>([&](auto I) {  // h=32 local: pairs (g, g+2); W = wq64 * W4^{g&1}
    constexpr int g = (I.v >> 1) * 4 + (I.v & 1);
    float2 A = X[g], B = X[g + 2];
    X[g] = make_float2(A.x + B.x, A.y + B.y);
    float2 d = cmul(make_float2(A.x - B.x, A.y - B.y), T.wq64);
    X[g + 2] = (g & 1) ? make_float2(d.y, -d.x) : d;
  });
  u_for<4>([&](auto I) {  // h=16 local: pairs (e, e+1); W = wq32 (uniform)
    constexpr int e = I.v * 2;
    float2 A = X[e], B = X[e + 1];
    X[e] = make_float2(A.x + B.x, A.y + B.y);
    X[e + 1] = cmul(make_float2(A.x - B.x, A.y - B.y), T.wq32);
  });
  u_for<8>([&](auto I) {  // h=8 cross (mask 8): W per-lane = ws8
    constexpr int i = I.v;
    float2 o = shxor(X[i], 8);
    X[i] = cmul(fma2(T.sg8, X[i], o), T.ws8);
  });
  u_for<8>([&](auto I) {  // h=4 cross (mask 4)
    constexpr int i = I.v;
    float2 o = shxor(X[i], 4);
    X[i] = cmul(fma2(T.sg4, X[i], o), T.ws4);
  });
  u_for<8>([&](auto I) {  // h=2 cross (mask 2)
    constexpr int i = I.v;
    float2 o = shxor(X[i], 2);
    X[i] = cmul(fma2(T.sg2, X[i], o), T.ws2);
  });
  u_for<8>([&](auto I) {  // h=1 cross (mask 1): W = 1
    constexpr int i = I.v;
    float2 o = shxor(X[i], 1);
    X[i] = fma2(T.sg1, X[i], o);
  });
}

// Inverse (DIT): exact mirror network, conj twiddles; bitrev in, natural out.
__device__ __forceinline__ void dit8(float2 (&X)[8], const Tw8& T) {
  u_for<8>([&](auto I) {  // h=1 cross
    constexpr int i = I.v;
    float2 o = shxor(X[i], 1);
    X[i] = fma2(T.sg1, X[i], o);
  });
  u_for<8>([&](auto I) {  // h=2 cross: u = mine*conj(ws2), exchange, fma
    constexpr int i = I.v;
    float2 u = cmulc(X[i], T.ws2);
    float2 o = shxor(u, 2);
    X[i] = fma2(T.sg2, u, o);
  });
  u_for<8>([&](auto I) {  // h=4 cross
    constexpr int i = I.v;
    float2 u = cmulc(X[i], T.ws4);
    float2 o = shxor(u, 4);
    X[i] = fma2(T.sg4, u, o);
  });
  u_for<8>([&](auto I) {  // h=8 cross
    constexpr int i = I.v;
    float2 u = cmulc(X[i], T.ws8);
    float2 o = shxor(u, 8);
    X[i] = fma2(T.sg8, u, o);
  });
  u_for<4>([&](auto I) {  // h=16 local
    constexpr int e = I.v * 2;
    float2 A = X[e];
    float2 t = cmulc(X[e + 1], T.wq32);
    X[e] = make_float2(A.x + t.x, A.y + t.y);
    X[e + 1] = make_float2(A.x - t.x, A.y - t.y);
  });
  u_for<4>([&](auto I) {  // h=32 local: conj(W4^{g&1}) = +i for odd g
    constexpr int g = (I.v >> 1) * 4 + (I.v & 1);
    float2 A = X[g];
    float2 t0 = cmulc(X[g + 2], T.wq64);
    float2 t = (g & 1) ? make_float2(-t0.y, t0.x) : t0;
    X[g] = make_float2(A.x + t.x, A.y + t.y);
    X[g + 2] = make_float2(A.x - t.x, A.y - t.y);
  });
  u_for<4>([&](auto I) {  // h=64 local: conj(W8^i) literal
    constexpr int i = I.v;
    float2 A = X[i];
    float2 t = mulW8c<i>(cmulc(X[i + 4], T.wq128));
    X[i] = make_float2(A.x + t.x, A.y + t.y);
    X[i + 4] = make_float2(A.x - t.x, A.y - t.y);
  });
}

// One block = one (k, mode). 1024 threads: q = t&15, gg = t>>4.
__global__ __launch_bounds__(1024)
void msp_mode(const float* __restrict__ V, const float* __restrict__ Pre,
              const float* __restrict__ Pim, const int* __restrict__ pos,
              float* __restrict__ out) {
  __shared__ float2 fld[TM * PITCH];  // 133,120 B field buffer (no swizzle)

  const int t = threadIdx.x;
  const int k = blockIdx.x >> 2;
  const int m = blockIdx.x & 3;
  const int q = t & 15;   // segment: owns positions q + 16*i
  const int gg = t >> 4;  // row (phase R) / col (phase C) group, 0..63

  // per-thread twiddle constants
  Tw8 T;
  float s, c;
  const float qf = (float)q;
  __sincosf(-PIF * qf / 64.0f, &s, &c);  T.wq128 = make_float2(c, s);
  __sincosf(-PIF * qf / 32.0f, &s, &c);  T.wq64  = make_float2(c, s);
  __sincosf(-PIF * qf / 16.0f, &s, &c);  T.wq32  = make_float2(c, s);
  if (q & 8) { __sincosf(-PIF * (float)(q & 7) / 8.0f, &s, &c); T.ws8 = make_float2(c, s); }
  else T.ws8 = make_float2(1.f, 0.f);
  if (q & 4) { __sincosf(-PIF * (float)(q & 3) / 4.0f, &s, &c); T.ws4 = make_float2(c, s); }
  else T.ws4 = make_float2(1.f, 0.f);
  T.ws2 = (q & 2) ? ((q & 1) ? make_float2(0.f, -1.f) : make_float2(1.f, 0.f))
                  : make_float2(1.f, 0.f);
  T.sg8 = (q & 8) ? -1.f : 1.f;
  T.sg4 = (q & 4) ? -1.f : 1.f;
  T.sg2 = (q & 2) ? -1.f : 1.f;
  T.sg1 = (q & 1) ? -1.f : 1.f;

  // per-thread H constants: ky(p=q+16i) = 8*rev4(q) + rev3(i)
  const int rev4q =
      ((q & 1) << 3) | ((q & 2) << 1) | ((q & 4) >> 1) | ((q & 8) >> 3);
  const float byf = (float)(8 * rev4q - ((q & 1) ? 128 : 0));  // iy base
  const float slope = 2.0f * PKF * byf;
  const float Pbase = PKF * byf * byf;

  const int p0 = pos[2 * k];
  const int p1 = pos[2 * k + 1];

  // load probe mode m directly into the LDS field
#pragma unroll 1
  for (int h = 0; h < 2; ++h) {
    const int y = gg + 64 * h;
    const float* pr = Pre + (m * TM + y) * TM + q;
    const float* pi = Pim + (m * TM + y) * TM + q;
    u_for<8>([&](auto I) {
      constexpr int i = I.v;
      fld[y * PITCH + q + 16 * i] = make_float2(pr[16 * i], pi[16 * i]);
    });
  }
  __syncthreads();

#pragma unroll 1
  for (int z = 0; z < TNZ; ++z) {
    // phase R: [rowI if z>0] -> T(z) -> rowF, per half
#pragma unroll 1
    for (int h = 0; h < 2; ++h) {
      const int y = gg + 64 * h;
      float2 X[8];
      u_for<8>([&](auto I) { X[I.v] = fld[y * PITCH + q + 16 * I.v]; });
      if (z > 0) dit8(X, T);
      const float* vb = V + (((z * TNY) + (p0 + y)) * TNX + p1 + q);
      u_for<8>([&](auto I) {
        constexpr int i = I.v;
        float v = vb[16 * i];
        float sv, cv;
        __sincosf(v, &sv, &cv);
        X[i] = cmul(X[i], make_float2(cv, sv));
      });
      dif8(X, T);
      u_for<8>([&](auto I) { fld[y * PITCH + q + 16 * I.v] = X[I.v]; });
    }
    __syncthreads();

    // phase C: colF -> [H -> colI] (or |.|^2 on the last slice)
    const bool last = (z == TNZ - 1);
#pragma unroll 1
    for (int h = 0; h < 2; ++h) {
      const int cc = gg + 64 * h;
      float2 X[8];
      u_for<8>([&](auto I) { X[I.v] = fld[(q + 16 * I.v) * PITCH + cc]; });
      dif8(X, T);
      if (!last) {
        const int kx = rev7(cc);
        const int ixf = kx - ((kx & 64) ? 128 : 0);
        const float P0 = Pbase + PKF * (float)(ixf * ixf);
        u_for<8>([&](auto I) {  // H at iy = byf + rev3(i); 1/N^2 folded
          constexpr int i = I.v;
          constexpr float r3f = (float)crev3(i);
          constexpr float Ci = (float)crev3(i) * (float)crev3(i);
          float ph = fmaf(slope, r3f, fmaf(PKF, Ci, P0));
          float sp, cp;
          __sincosf(ph, &sp, &cp);
          X[i] = cmul(X[i], make_float2(cp * INV_N2, sp * INV_N2));
        });
        dit8(X, T);
        u_for<8>([&](auto I) { fld[(q + 16 * I.v) * PITCH + cc] = X[I.v]; });
      } else {
        u_for<8>([&](auto I) {  // |psi_f|^2 back to the same slots (no race)
          constexpr int i = I.v;
          float v = fmaf(X[i].x, X[i].x, X[i].y * X[i].y);
          fld[(q + 16 * i) * PITCH + cc] = make_float2(v, v);
        });
      }
    }
    __syncthreads();
  }

  // gather (un-bit-reverse) and coalesced global atomic accumulate
  float* ob = out + k * (TM * TM);
#pragma unroll
  for (int ii = 0; ii < 16; ++ii) {
    const int idx = t + 1024 * ii;
    const int ky = idx >> 7, kx = idx & 127;
    atomicAdd(&ob[idx], fld[rev7(ky) * PITCH + rev7(kx)].x);
  }
}

__global__ __launch_bounds__(256) void zero_k(float4* __restrict__ p, int n4) {
  const int i = blockIdx.x * 256 + threadIdx.x;
  if (i < n4) p[i] = make_float4(0.f, 0.f, 0.f, 0.f);
}

__global__ __launch_bounds__(256) void sqrt_k(float* __restrict__ p, int n) {
  const int i = blockIdx.x * 256 + threadIdx.x;
  if (i < n) p[i] = sqrtf(EPSV + p[i] * INV_N2);  // ortho: 1/N^2 on |.|^2
}

}  // namespace

extern "C" void kernel_launch(void* const* d_in, const int* in_sizes, int n_in,
                              void* d_out, int out_size, void* d_ws, size_t ws_size,
                              hipStream_t stream) {
  (void)in_sizes; (void)n_in; (void)d_ws; (void)ws_size;
  const float* V = (const float*)d_in[0];
  const float* Pre = (const float*)d_in[1];
  const float* Pim = (const float*)d_in[2];
  const int* pos = (const int*)d_in[3];
  float* out = (float*)d_out;
  const int n = out_size;  // 256*128*128
  const int n4 = n >> 2;
  zero_k<<<dim3((n4 + 255) / 256), dim3(256), 0, stream>>>((float4*)out, n4);
  msp_mode<<<dim3(1024), dim3(1024), 0, stream>>>(V, Pre, Pim, pos, out);
  sqrt_k<<<dim3((n + 255) / 256), dim3(256), 0, stream>>>(out, n);
}

// Round 12
// 606.552 us; speedup vs baseline: 3.7152x; 1.3772x over previous
//
#include <hip/hip_runtime.h>
#include <math.h>

namespace {

constexpr int TNZ = 8, TNY = 512, TNX = 512, TM = 128;
constexpr int PITCH = 130;  // float2 pitch; 130 % 16 == 2 rotates banks naturally
constexpr float F0 = 1.0f / (TM * 0.2f);
constexpr float PK = -3.14159265358979323846f * 0.025f * 10.0f;
constexpr float PKF = PK * F0 * F0;  // phase = PKF * (iy^2 + ix^2)
constexpr float INV_N2 = 1.0f / (TM * TM);
constexpr float EPSV = 1e-10f;
constexpr float PIF = 3.14159265358979323846f;
constexpr float RT2H = 0.70710678118654752440f;

// compile-time-index unroll helper
template <int I> struct Ic { static constexpr int v = I; };
template <int I, int N, typename F>
__device__ __forceinline__ void u_impl(F&& f) {
  if constexpr (I < N) { f(Ic<I>{}); u_impl<I + 1, N>(f); }
}
template <int N, typename F>
__device__ __forceinline__ void u_for(F&& f) { u_impl<0, N>(f); }

__device__ __forceinline__ float2 cmul(float2 a, float2 b) {
  return make_float2(a.x * b.x - a.y * b.y, a.x * b.y + a.y * b.x);
}
__device__ __forceinline__ float2 cmulc(float2 a, float2 b) {  // a * conj(b)
  return make_float2(a.x * b.x + a.y * b.y, a.y * b.x - a.x * b.y);
}
// lane^1 / lane^2 exchange on the VALU pipe (DPP quad_perm; all 64 lanes)
template <int CTRL>
__device__ __forceinline__ float dppf(float v) {
  return __int_as_float(
      __builtin_amdgcn_mov_dpp(__float_as_int(v), CTRL, 0xF, 0xF, true));
}
template <int M>  // M = 1 or 2
__device__ __forceinline__ float2 shdpp(float2 v) {
  constexpr int CTRL = (M == 1) ? 0xB1 : 0x4E;
  return make_float2(dppf<CTRL>(v.x), dppf<CTRL>(v.y));
}
// lane^4 / lane^8 exchange via explicit ds_swizzle (BitMode xor patterns)
template <int M>  // M = 4 or 8
__device__ __forceinline__ float2 shswz(float2 v) {
  constexpr int PAT = (M << 10) | 0x1F;
  return make_float2(
      __int_as_float(__builtin_amdgcn_ds_swizzle(__float_as_int(v.x), PAT)),
      __int_as_float(__builtin_amdgcn_ds_swizzle(__float_as_int(v.y), PAT)));
}
__device__ __forceinline__ float2 fma2(float sg, float2 mine, float2 oth) {
  return make_float2(fmaf(sg, mine.x, oth.x), fmaf(sg, mine.y, oth.y));
}
__device__ __forceinline__ int rev7(int n) {
  return ((n & 1) << 6) | ((n & 2) << 4) | ((n & 4) << 2) | (n & 8) |
         ((n & 16) >> 2) | ((n & 32) >> 4) | ((n & 64) >> 6);
}
constexpr int crev3(int i) { return ((i & 1) << 2) | (i & 2) | ((i & 4) >> 2); }

// multiply by W8^i (literal): W8 = exp(-i*pi/4)
template <int i> __device__ __forceinline__ float2 mulW8(float2 t) {
  if constexpr (i == 0) return t;
  else if constexpr (i == 1)
    return make_float2(RT2H * (t.x + t.y), RT2H * (t.y - t.x));
  else if constexpr (i == 2) return make_float2(t.y, -t.x);
  else return make_float2(RT2H * (t.y - t.x), -RT2H * (t.x + t.y));
}
// multiply by conj(W8^i)
template <int i> __device__ __forceinline__ float2 mulW8c(float2 t) {
  if constexpr (i == 0) return t;
  else if constexpr (i == 1)
    return make_float2(RT2H * (t.x - t.y), RT2H * (t.x + t.y));
  else if constexpr (i == 2) return make_float2(-t.y, t.x);
  else return make_float2(-RT2H * (t.x + t.y), RT2H * (t.x - t.y));
}

struct Tw8 {
  float2 wq128, wq64, wq32;  // W128^q, W64^q, W32^q
  float2 ws8, ws4, ws2;      // upper-lane stage twiddles (lower lanes: 1)
  float sg8, sg4, sg2, sg1;  // butterfly signs per lane
};

// ---- FFT-128, ownership p = q + 16*i (q = lane&15, i = reg 0..7) ----
// DIF forward: natural position order in, bit-reversed order out.
__device__ __forceinline__ void dif8(float2 (&X)[8], const Tw8& T) {
  u_for<4>([&](auto I) {  // h=64 local: pairs (i, i+4); W = wq128 * W8^i
    constexpr int i = I.v;
    float2 A = X[i], B = X[i + 4];
    X[i] = make_float2(A.x + B.x, A.y + B.y);
    float2 d = make_float2(A.x - B.x, A.y - B.y);
    X[i + 4] = mulW8<i>(cmul(d, T.wq128));
  });
  u_for<4>([&](auto I) {  // h=32 local: pairs (g, g+2); W = wq64 * W4^{g&1}
    constexpr int g = (I.v >> 1) * 4 + (I.v & 1);
    float2 A = X[g], B = X[g + 2];
    X[g] = make_float2(A.x + B.x, A.y + B.y);
    float2 d = cmul(make_float2(A.x - B.x, A.y - B.y), T.wq64);
    X[g + 2] = (g & 1) ? make_float2(d.y, -d.x) : d;
  });
  u_for<4>([&](auto I) {  // h=16 local: pairs (e, e+1); W = wq32 (uniform)
    constexpr int e = I.v * 2;
    float2 A = X[e], B = X[e + 1];
    X[e] = make_float2(A.x + B.x, A.y + B.y);
    X[e + 1] = cmul(make_float2(A.x - B.x, A.y - B.y), T.wq32);
  });
  u_for<8>([&](auto I) {  // h=8 cross (mask 8, DS): W per-lane = ws8
    constexpr int i = I.v;
    float2 o = shswz<8>(X[i]);
    X[i] = cmul(fma2(T.sg8, X[i], o), T.ws8);
  });
  u_for<8>([&](auto I) {  // h=4 cross (mask 4, DS)
    constexpr int i = I.v;
    float2 o = shswz<4>(X[i]);
    X[i] = cmul(fma2(T.sg4, X[i], o), T.ws4);
  });
  u_for<8>([&](auto I) {  // h=2 cross (mask 2, DPP/VALU)
    constexpr int i = I.v;
    float2 o = shdpp<2>(X[i]);
    X[i] = cmul(fma2(T.sg2, X[i], o), T.ws2);
  });
  u_for<8>([&](auto I) {  // h=1 cross (mask 1, DPP/VALU): W = 1
    constexpr int i = I.v;
    float2 o = shdpp<1>(X[i]);
    X[i] = fma2(T.sg1, X[i], o);
  });
}

// Inverse (DIT): exact mirror network, conj twiddles; bitrev in, natural out.
__device__ __forceinline__ void dit8(float2 (&X)[8], const Tw8& T) {
  u_for<8>([&](auto I) {  // h=1 cross (DPP)
    constexpr int i = I.v;
    float2 o = shdpp<1>(X[i]);
    X[i] = fma2(T.sg1, X[i], o);
  });
  u_for<8>([&](auto I) {  // h=2 cross (DPP): u = mine*conj(ws2), exchange, fma
    constexpr int i = I.v;
    float2 u = cmulc(X[i], T.ws2);
    float2 o = shdpp<2>(u);
    X[i] = fma2(T.sg2, u, o);
  });
  u_for<8>([&](auto I) {  // h=4 cross (DS)
    constexpr int i = I.v;
    float2 u = cmulc(X[i], T.ws4);
    float2 o = shswz<4>(u);
    X[i] = fma2(T.sg4, u, o);
  });
  u_for<8>([&](auto I) {  // h=8 cross (DS)
    constexpr int i = I.v;
    float2 u = cmulc(X[i], T.ws8);
    float2 o = shswz<8>(u);
    X[i] = fma2(T.sg8, u, o);
  });
  u_for<4>([&](auto I) {  // h=16 local
    constexpr int e = I.v * 2;
    float2 A = X[e];
    float2 t = cmulc(X[e + 1], T.wq32);
    X[e] = make_float2(A.x + t.x, A.y + t.y);
    X[e + 1] = make_float2(A.x - t.x, A.y - t.y);
  });
  u_for<4>([&](auto I) {  // h=32 local: conj(W4^{g&1}) = +i for odd g
    constexpr int g = (I.v >> 1) * 4 + (I.v & 1);
    float2 A = X[g];
    float2 t0 = cmulc(X[g + 2], T.wq64);
    float2 t = (g & 1) ? make_float2(-t0.y, t0.x) : t0;
    X[g] = make_float2(A.x + t.x, A.y + t.y);
    X[g + 2] = make_float2(A.x - t.x, A.y - t.y);
  });
  u_for<4>([&](auto I) {  // h=64 local: conj(W8^i) literal
    constexpr int i = I.v;
    float2 A = X[i];
    float2 t = mulW8c<i>(cmulc(X[i + 4], T.wq128));
    X[i] = make_float2(A.x + t.x, A.y + t.y);
    X[i + 4] = make_float2(A.x - t.x, A.y - t.y);
  });
}

// One block = one (k, mode). 1024 threads: q = t&15, gg = t>>4.
__global__ __launch_bounds__(1024)
void msp_mode(const float* __restrict__ V, const float* __restrict__ Pre,
              const float* __restrict__ Pim, const int* __restrict__ pos,
              float* __restrict__ out) {
  __shared__ float2 fld[TM * PITCH];  // 133,120 B field buffer (no swizzle)

  const int t = threadIdx.x;
  const int k = blockIdx.x >> 2;
  const int m = blockIdx.x & 3;
  const int q = t & 15;   // segment: owns positions q + 16*i
  const int gg = t >> 4;  // row (phase R) / col (phase C) group, 0..63

  // per-thread twiddle constants
  Tw8 T;
  float s, c;
  const float qf = (float)q;
  __sincosf(-PIF * qf / 64.0f, &s, &c);  T.wq128 = make_float2(c, s);
  __sincosf(-PIF * qf / 32.0f, &s, &c);  T.wq64  = make_float2(c, s);
  __sincosf(-PIF * qf / 16.0f, &s, &c);  T.wq32  = make_float2(c, s);
  if (q & 8) { __sincosf(-PIF * (float)(q & 7) / 8.0f, &s, &c); T.ws8 = make_float2(c, s); }
  else T.ws8 = make_float2(1.f, 0.f);
  if (q & 4) { __sincosf(-PIF * (float)(q & 3) / 4.0f, &s, &c); T.ws4 = make_float2(c, s); }
  else T.ws4 = make_float2(1.f, 0.f);
  T.ws2 = (q & 2) ? ((q & 1) ? make_float2(0.f, -1.f) : make_float2(1.f, 0.f))
                  : make_float2(1.f, 0.f);
  T.sg8 = (q & 8) ? -1.f : 1.f;
  T.sg4 = (q & 4) ? -1.f : 1.f;
  T.sg2 = (q & 2) ? -1.f : 1.f;
  T.sg1 = (q & 1) ? -1.f : 1.f;

  // per-thread H constants: ky(p=q+16i) = 8*rev4(q) + rev3(i)
  const int rev4q =
      ((q & 1) << 3) | ((q & 2) << 1) | ((q & 4) >> 1) | ((q & 8) >> 3);
  const float byf = (float)(8 * rev4q - ((q & 1) ? 128 : 0));  // iy base
  const float slope = 2.0f * PKF * byf;
  const float Pbase = PKF * byf * byf;

  const int p0 = pos[2 * k];
  const int p1 = pos[2 * k + 1];

  // load probe mode m directly into the LDS field
#pragma unroll 1
  for (int h = 0; h < 2; ++h) {
    const int y = gg + 64 * h;
    const float* pr = Pre + (m * TM + y) * TM + q;
    const float* pi = Pim + (m * TM + y) * TM + q;
    u_for<8>([&](auto I) {
      constexpr int i = I.v;
      fld[y * PITCH + q + 16 * i] = make_float2(pr[16 * i], pi[16 * i]);
    });
  }
  __syncthreads();

#pragma unroll 1
  for (int z = 0; z < TNZ; ++z) {
    // phase R: [rowI if z>0] -> T(z) -> rowF, per half
#pragma unroll 1
    for (int h = 0; h < 2; ++h) {
      const int y = gg + 64 * h;
      float2 X[8];
      u_for<8>([&](auto I) { X[I.v] = fld[y * PITCH + q + 16 * I.v]; });
      if (z > 0) dit8(X, T);
      const float* vb = V + (((z * TNY) + (p0 + y)) * TNX + p1 + q);
      u_for<8>([&](auto I) {
        constexpr int i = I.v;
        float v = vb[16 * i];
        float sv, cv;
        __sincosf(v, &sv, &cv);
        X[i] = cmul(X[i], make_float2(cv, sv));
      });
      dif8(X, T);
      u_for<8>([&](auto I) { fld[y * PITCH + q + 16 * I.v] = X[I.v]; });
    }
    __syncthreads();

    // phase C: colF -> [H -> colI] (or |.|^2 scatter on the last slice)
    const bool last = (z == TNZ - 1);
#pragma unroll 1
    for (int h = 0; h < 2; ++h) {
      const int cc = gg + 64 * h;
      float2 X[8];
      u_for<8>([&](auto I) { X[I.v] = fld[(q + 16 * I.v) * PITCH + cc]; });
      dif8(X, T);
      if (!last) {
        const int kx = rev7(cc);
        const int ixf = kx - ((kx & 64) ? 128 : 0);
        const float P0 = Pbase + PKF * (float)(ixf * ixf);
        u_for<8>([&](auto I) {  // H at iy = byf + rev3(i); 1/N^2 folded
          constexpr int i = I.v;
          constexpr float r3f = (float)crev3(i);
          constexpr float Ci = (float)crev3(i) * (float)crev3(i);
          float ph = fmaf(slope, r3f, fmaf(PKF, Ci, P0));
          float sp, cp;
          __sincosf(ph, &sp, &cp);
          X[i] = cmul(X[i], make_float2(cp * INV_N2, sp * INV_N2));
        });
        dit8(X, T);
        u_for<8>([&](auto I) { fld[(q + 16 * I.v) * PITCH + cc] = X[I.v]; });
      } else {
        // |psi_f|^2 scattered to natural frequency (ky,kx'), float view.
        // ky = 8*rev4q + rev3(i); kx' = rev7(cc) ^ rev4q (bank-spread XOR).
        float* fldf = reinterpret_cast<float*>(fld);
        const int kxn = rev7(cc) ^ rev4q;
        u_for<8>([&](auto I) {
          constexpr int i = I.v;
          const int ky = 8 * rev4q + crev3(i);
          float v = fmaf(X[i].x, X[i].x, X[i].y * X[i].y);
          fldf[ky * (2 * PITCH) + kxn] = v;
        });
      }
    }
    __syncthreads();
  }

  // gather (linear, conflict-free, coalesced) and global atomic accumulate
  const float* fldf = reinterpret_cast<const float*>(fld);
  float* ob = out + k * (TM * TM);
#pragma unroll
  for (int ii = 0; ii < 16; ++ii) {
    const int idx = t + 1024 * ii;
    const int ky = idx >> 7, kx = idx & 127;
    const int kxn = kx ^ ((ky >> 3) & 15);
    atomicAdd(&ob[idx], fldf[ky * (2 * PITCH) + kxn]);
  }
}

__global__ __launch_bounds__(256) void zero_k(float4* __restrict__ p, int n4) {
  const int i = blockIdx.x * 256 + threadIdx.x;
  if (i < n4) p[i] = make_float4(0.f, 0.f, 0.f, 0.f);
}

__global__ __launch_bounds__(256) void sqrt_k(float* __restrict__ p, int n) {
  const int i = blockIdx.x * 256 + threadIdx.x;
  if (i < n) p[i] = sqrtf(EPSV + p[i] * INV_N2);  // ortho: 1/N^2 on |.|^2
}

}  // namespace

extern "C" void kernel_launch(void* const* d_in, const int* in_sizes, int n_in,
                              void* d_out, int out_size, void* d_ws, size_t ws_size,
                              hipStream_t stream) {
  (void)in_sizes; (void)n_in; (void)d_ws; (void)ws_size;
  const float* V = (const float*)d_in[0];
  const float* Pre = (const float*)d_in[1];
  const float* Pim = (const float*)d_in[2];
  const int* pos = (const int*)d_in[3];
  float* out = (float*)d_out;
  const int n = out_size;  // 256*128*128
  const int n4 = n >> 2;
  zero_k<<<dim3((n4 + 255) / 256), dim3(256), 0, stream>>>((float4*)out, n4);
  msp_mode<<<dim3(1024), dim3(1024), 0, stream>>>(V, Pre, Pim, pos, out);
  sqrt_k<<<dim3((n + 255) / 256), dim3(256), 0, stream>>>(out, n);
}

// Round 13
// 540.788 us; speedup vs baseline: 4.1670x; 1.1216x over previous
//
#include <hip/hip_runtime.h>
#include <math.h>

namespace {

constexpr int TNZ = 8, TNY = 512, TNX = 512, TM = 128;
constexpr int PITCH = 130;  // v2 pitch; 130 % 16 == 2 rotates banks naturally
constexpr float F0 = 1.0f / (TM * 0.2f);
constexpr float PK = -3.14159265358979323846f * 0.025f * 10.0f;
constexpr float PKF = PK * F0 * F0;  // phase = PKF * (iy^2 + ix^2)
constexpr float INV_N2 = 1.0f / (TM * TM);
constexpr float EPSV = 1e-10f;
constexpr float PIF = 3.14159265358979323846f;
constexpr float RT2H = 0.70710678118654752440f;

// packed float2 (lowers to v_pk_* VOP3P on gfx950)
typedef float v2 __attribute__((ext_vector_type(2)));
__device__ __forceinline__ v2 mk2(float x, float y) {
  v2 r; r.x = x; r.y = y; return r;
}

// compile-time-index unroll helper
template <int I> struct Ic { static constexpr int v = I; };
template <int I, int N, typename F>
__device__ __forceinline__ void u_impl(F&& f) {
  if constexpr (I < N) { f(Ic<I>{}); u_impl<I + 1, N>(f); }
}
template <int N, typename F>
__device__ __forceinline__ void u_for(F&& f) { u_impl<0, N>(f); }

// complex mul: (ar*br - ai*bi, ar*bi + ai*br) = pk_mul + pk_fma
__device__ __forceinline__ v2 cmul(v2 a, v2 b) {
  v2 p = a.xx * b;
  return __builtin_elementwise_fma(mk2(-a.y, a.y), b.yx, p);
}
// a * conj(b): (ar*br + ai*bi, ai*br - ar*bi)
__device__ __forceinline__ v2 cmulc(v2 a, v2 b) {
  v2 p = a.xx * mk2(b.x, -b.y);
  return __builtin_elementwise_fma(a.yy, b.yx, p);
}
__device__ __forceinline__ v2 fma2(float sg, v2 mine, v2 oth) {
  return __builtin_elementwise_fma(mk2(sg, sg), mine, oth);
}
// lane^1 / lane^2 exchange on the VALU pipe (DPP quad_perm; all 64 lanes)
template <int CTRL>
__device__ __forceinline__ float dppf(float v) {
  return __int_as_float(
      __builtin_amdgcn_mov_dpp(__float_as_int(v), CTRL, 0xF, 0xF, true));
}
template <int M>  // M = 1 or 2
__device__ __forceinline__ v2 shdpp(v2 v) {
  constexpr int CTRL = (M == 1) ? 0xB1 : 0x4E;
  return mk2(dppf<CTRL>(v.x), dppf<CTRL>(v.y));
}
// lane^4 / lane^8 exchange via explicit ds_swizzle (BitMode xor patterns)
template <int M>  // M = 4 or 8
__device__ __forceinline__ v2 shswz(v2 v) {
  constexpr int PAT = (M << 10) | 0x1F;
  return mk2(
      __int_as_float(__builtin_amdgcn_ds_swizzle(__float_as_int(v.x), PAT)),
      __int_as_float(__builtin_amdgcn_ds_swizzle(__float_as_int(v.y), PAT)));
}
__device__ __forceinline__ int rev7(int n) {
  return ((n & 1) << 6) | ((n & 2) << 4) | ((n & 4) << 2) | (n & 8) |
         ((n & 16) >> 2) | ((n & 32) >> 4) | ((n & 64) >> 6);
}
constexpr int crev3(int i) { return ((i & 1) << 2) | (i & 2) | ((i & 4) >> 2); }

// multiply by W8^i (literal): W8 = exp(-i*pi/4)
template <int i> __device__ __forceinline__ v2 mulW8(v2 t) {
  if constexpr (i == 0) return t;
  else if constexpr (i == 1) return (t + mk2(t.y, -t.x)) * RT2H;
  else if constexpr (i == 2) return mk2(t.y, -t.x);
  else return (mk2(t.y, -t.x) - t) * RT2H;
}
// multiply by conj(W8^i)
template <int i> __device__ __forceinline__ v2 mulW8c(v2 t) {
  if constexpr (i == 0) return t;
  else if constexpr (i == 1) return (t + mk2(-t.y, t.x)) * RT2H;
  else if constexpr (i == 2) return mk2(-t.y, t.x);
  else return (mk2(-t.y, t.x) - t) * RT2H;
}

struct Tw8 {
  v2 wq128, wq64, wq32;  // W128^q, W64^q, W32^q
  v2 ws8, ws4, ws2;      // upper-lane stage twiddles (lower lanes: 1)
  float sg8, sg4, sg2, sg1;  // butterfly signs per lane
};

// ---- FFT-128, ownership p = q + 16*i (q = lane&15, i = reg 0..7) ----
// DIF forward: natural position order in, bit-reversed order out.
__device__ __forceinline__ void dif8(v2 (&X)[8], const Tw8& T) {
  u_for<4>([&](auto I) {  // h=64 local: pairs (i, i+4); W = wq128 * W8^i
    constexpr int i = I.v;
    v2 A = X[i], B = X[i + 4];
    X[i] = A + B;
    X[i + 4] = mulW8<i>(cmul(A - B, T.wq128));
  });
  u_for<4>([&](auto I) {  // h=32 local: pairs (g, g+2); W = wq64 * W4^{g&1}
    constexpr int g = (I.v >> 1) * 4 + (I.v & 1);
    v2 A = X[g], B = X[g + 2];
    X[g] = A + B;
    v2 d = cmul(A - B, T.wq64);
    X[g + 2] = (g & 1) ? mk2(d.y, -d.x) : d;
  });
  u_for<4>([&](auto I) {  // h=16 local: pairs (e, e+1); W = wq32 (uniform)
    constexpr int e = I.v * 2;
    v2 A = X[e], B = X[e + 1];
    X[e] = A + B;
    X[e + 1] = cmul(A - B, T.wq32);
  });
  u_for<8>([&](auto I) {  // h=8 cross (mask 8, DS): W per-lane = ws8
    constexpr int i = I.v;
    v2 o = shswz<8>(X[i]);
    X[i] = cmul(fma2(T.sg8, X[i], o), T.ws8);
  });
  u_for<8>([&](auto I) {  // h=4 cross (mask 4, DS)
    constexpr int i = I.v;
    v2 o = shswz<4>(X[i]);
    X[i] = cmul(fma2(T.sg4, X[i], o), T.ws4);
  });
  u_for<8>([&](auto I) {  // h=2 cross (mask 2, DPP/VALU)
    constexpr int i = I.v;
    v2 o = shdpp<2>(X[i]);
    X[i] = cmul(fma2(T.sg2, X[i], o), T.ws2);
  });
  u_for<8>([&](auto I) {  // h=1 cross (mask 1, DPP/VALU): W = 1
    constexpr int i = I.v;
    v2 o = shdpp<1>(X[i]);
    X[i] = fma2(T.sg1, X[i], o);
  });
}

// Inverse (DIT): exact mirror network, conj twiddles; bitrev in, natural out.
__device__ __forceinline__ void dit8(v2 (&X)[8], const Tw8& T) {
  u_for<8>([&](auto I) {  // h=1 cross (DPP)
    constexpr int i = I.v;
    v2 o = shdpp<1>(X[i]);
    X[i] = fma2(T.sg1, X[i], o);
  });
  u_for<8>([&](auto I) {  // h=2 cross (DPP): u = mine*conj(ws2), exchange, fma
    constexpr int i = I.v;
    v2 u = cmulc(X[i], T.ws2);
    v2 o = shdpp<2>(u);
    X[i] = fma2(T.sg2, u, o);
  });
  u_for<8>([&](auto I) {  // h=4 cross (DS)
    constexpr int i = I.v;
    v2 u = cmulc(X[i], T.ws4);
    v2 o = shswz<4>(u);
    X[i] = fma2(T.sg4, u, o);
  });
  u_for<8>([&](auto I) {  // h=8 cross (DS)
    constexpr int i = I.v;
    v2 u = cmulc(X[i], T.ws8);
    v2 o = shswz<8>(u);
    X[i] = fma2(T.sg8, u, o);
  });
  u_for<4>([&](auto I) {  // h=16 local
    constexpr int e = I.v * 2;
    v2 A = X[e];
    v2 t = cmulc(X[e + 1], T.wq32);
    X[e] = A + t;
    X[e + 1] = A - t;
  });
  u_for<4>([&](auto I) {  // h=32 local: conj(W4^{g&1}) = +i for odd g
    constexpr int g = (I.v >> 1) * 4 + (I.v & 1);
    v2 A = X[g];
    v2 t0 = cmulc(X[g + 2], T.wq64);
    v2 t = (g & 1) ? mk2(-t0.y, t0.x) : t0;
    X[g] = A + t;
    X[g + 2] = A - t;
  });
  u_for<4>([&](auto I) {  // h=64 local: conj(W8^i) literal
    constexpr int i = I.v;
    v2 A = X[i];
    v2 t = mulW8c<i>(cmulc(X[i + 4], T.wq128));
    X[i] = A + t;
    X[i + 4] = A - t;
  });
}

// One block = one (k, mode). 1024 threads: q = t&15, gg = t>>4.
__global__ __launch_bounds__(1024)
void msp_mode(const float* __restrict__ V, const float* __restrict__ Pre,
              const float* __restrict__ Pim, const int* __restrict__ pos,
              float* __restrict__ out) {
  __shared__ v2 fld[TM * PITCH];  // 133,120 B field buffer (no swizzle)

  const int t = threadIdx.x;
  const int k = blockIdx.x >> 2;
  const int m = blockIdx.x & 3;
  const int q = t & 15;   // segment: owns positions q + 16*i
  const int gg = t >> 4;  // row (phase R) / col (phase C) group, 0..63

  // per-thread twiddle constants
  Tw8 T;
  float s, c;
  const float qf = (float)q;
  __sincosf(-PIF * qf / 64.0f, &s, &c);  T.wq128 = mk2(c, s);
  __sincosf(-PIF * qf / 32.0f, &s, &c);  T.wq64  = mk2(c, s);
  __sincosf(-PIF * qf / 16.0f, &s, &c);  T.wq32  = mk2(c, s);
  if (q & 8) { __sincosf(-PIF * (float)(q & 7) / 8.0f, &s, &c); T.ws8 = mk2(c, s); }
  else T.ws8 = mk2(1.f, 0.f);
  if (q & 4) { __sincosf(-PIF * (float)(q & 3) / 4.0f, &s, &c); T.ws4 = mk2(c, s); }
  else T.ws4 = mk2(1.f, 0.f);
  T.ws2 = (q & 2) ? ((q & 1) ? mk2(0.f, -1.f) : mk2(1.f, 0.f)) : mk2(1.f, 0.f);
  T.sg8 = (q & 8) ? -1.f : 1.f;
  T.sg4 = (q & 4) ? -1.f : 1.f;
  T.sg2 = (q & 2) ? -1.f : 1.f;
  T.sg1 = (q & 1) ? -1.f : 1.f;

  // per-thread H constants: ky(p=q+16i) = 8*rev4(q) + rev3(i)
  const int rev4q =
      ((q & 1) << 3) | ((q & 2) << 1) | ((q & 4) >> 1) | ((q & 8) >> 3);
  const float byf = (float)(8 * rev4q - ((q & 1) ? 128 : 0));  // iy base
  const float slope = 2.0f * PKF * byf;
  const float Pbase = PKF * byf * byf;

  const int p0 = pos[2 * k];
  const int p1 = pos[2 * k + 1];

  // load probe mode m directly into the LDS field
#pragma unroll 1
  for (int h = 0; h < 2; ++h) {
    const int y = gg + 64 * h;
    const float* pr = Pre + (m * TM + y) * TM + q;
    const float* pi = Pim + (m * TM + y) * TM + q;
    u_for<8>([&](auto I) {
      constexpr int i = I.v;
      fld[y * PITCH + q + 16 * i] = mk2(pr[16 * i], pi[16 * i]);
    });
  }
  __syncthreads();

#pragma unroll 1
  for (int z = 0; z < TNZ; ++z) {
    // phase R: [rowI if z>0] -> T(z) -> rowF, per half
#pragma unroll 1
    for (int h = 0; h < 2; ++h) {
      const int y = gg + 64 * h;
      v2 X[8];
      u_for<8>([&](auto I) { X[I.v] = fld[y * PITCH + q + 16 * I.v]; });
      if (z > 0) dit8(X, T);
      const float* vb = V + (((z * TNY) + (p0 + y)) * TNX + p1 + q);
      u_for<8>([&](auto I) {
        constexpr int i = I.v;
        float v = vb[16 * i];
        float sv, cv;
        __sincosf(v, &sv, &cv);
        X[i] = cmul(X[i], mk2(cv, sv));
      });
      dif8(X, T);
      u_for<8>([&](auto I) { fld[y * PITCH + q + 16 * I.v] = X[I.v]; });
    }
    __syncthreads();

    // phase C: colF -> [H -> colI] (or |.|^2 scatter on the last slice)
    const bool last = (z == TNZ - 1);
#pragma unroll 1
    for (int h = 0; h < 2; ++h) {
      const int cc = gg + 64 * h;
      v2 X[8];
      u_for<8>([&](auto I) { X[I.v] = fld[(q + 16 * I.v) * PITCH + cc]; });
      dif8(X, T);
      if (!last) {
        const int kx = rev7(cc);
        const int ixf = kx - ((kx & 64) ? 128 : 0);
        const float P0 = Pbase + PKF * (float)(ixf * ixf);
        u_for<8>([&](auto I) {  // H at iy = byf + rev3(i); 1/N^2 folded
          constexpr int i = I.v;
          constexpr float r3f = (float)crev3(i);
          constexpr float Ci = (float)crev3(i) * (float)crev3(i);
          float ph = fmaf(slope, r3f, fmaf(PKF, Ci, P0));
          float sp, cp;
          __sincosf(ph, &sp, &cp);
          X[i] = cmul(X[i], mk2(cp * INV_N2, sp * INV_N2));
        });
        dit8(X, T);
        u_for<8>([&](auto I) { fld[(q + 16 * I.v) * PITCH + cc] = X[I.v]; });
      } else {
        // |psi_f|^2 scattered to natural frequency (ky,kx'), float view.
        // ky = 8*rev4q + rev3(i); kx' = rev7(cc) ^ rev4q (bank-spread XOR).
        float* fldf = reinterpret_cast<float*>(fld);
        const int kxn = rev7(cc) ^ rev4q;
        u_for<8>([&](auto I) {
          constexpr int i = I.v;
          const int ky = 8 * rev4q + crev3(i);
          float v = fmaf(X[i].x, X[i].x, X[i].y * X[i].y);
          fldf[ky * (2 * PITCH) + kxn] = v;
        });
      }
    }
    __syncthreads();
  }

  // gather (linear, conflict-free, coalesced) and global atomic accumulate
  const float* fldf = reinterpret_cast<const float*>(fld);
  float* ob = out + k * (TM * TM);
#pragma unroll
  for (int ii = 0; ii < 16; ++ii) {
    const int idx = t + 1024 * ii;
    const int ky = idx >> 7, kx = idx & 127;
    const int kxn = kx ^ ((ky >> 3) & 15);
    atomicAdd(&ob[idx], fldf[ky * (2 * PITCH) + kxn]);
  }
}

__global__ __launch_bounds__(256) void zero_k(float4* __restrict__ p, int n4) {
  const int i = blockIdx.x * 256 + threadIdx.x;
  if (i < n4) p[i] = make_float4(0.f, 0.f, 0.f, 0.f);
}

__global__ __launch_bounds__(256) void sqrt_k(float* __restrict__ p, int n) {
  const int i = blockIdx.x * 256 + threadIdx.x;
  if (i < n) p[i] = sqrtf(EPSV + p[i] * INV_N2);  // ortho: 1/N^2 on |.|^2
}

}  // namespace

extern "C" void kernel_launch(void* const* d_in, const int* in_sizes, int n_in,
                              void* d_out, int out_size, void* d_ws, size_t ws_size,
                              hipStream_t stream) {
  (void)in_sizes; (void)n_in; (void)d_ws; (void)ws_size;
  const float* V = (const float*)d_in[0];
  const float* Pre = (const float*)d_in[1];
  const float* Pim = (const float*)d_in[2];
  const int* pos = (const int*)d_in[3];
  float* out = (float*)d_out;
  const int n = out_size;  // 256*128*128
  const int n4 = n >> 2;
  zero_k<<<dim3((n4 + 255) / 256), dim3(256), 0, stream>>>((float4*)out, n4);
  msp_mode<<<dim3(1024), dim3(1024), 0, stream>>>(V, Pre, Pim, pos, out);
  sqrt_k<<<dim3((n + 255) / 256), dim3(256), 0, stream>>>(out, n);
}

// Round 14
// 535.106 us; speedup vs baseline: 4.2112x; 1.0106x over previous
//
#include <hip/hip_runtime.h>
#include <math.h>

namespace {

constexpr int TNZ = 8, TNY = 512, TNX = 512, TM = 128;
constexpr int PITCH = 130;  // v2 pitch; 130 % 16 == 2 rotates banks naturally
constexpr float F0 = 1.0f / (TM * 0.2f);
constexpr float PK = -3.14159265358979323846f * 0.025f * 10.0f;
constexpr float PKF = PK * F0 * F0;  // phase = PKF * (iy^2 + ix^2)
constexpr float INV_N2 = 1.0f / (TM * TM);
constexpr float EPSV = 1e-10f;
constexpr float PIF = 3.14159265358979323846f;
constexpr float RT2H = 0.70710678118654752440f;

// packed float2 (lowers to v_pk_* VOP3P on gfx950)
typedef float v2 __attribute__((ext_vector_type(2)));
__device__ __forceinline__ v2 mk2(float x, float y) {
  v2 r; r.x = x; r.y = y; return r;
}

// compile-time-index unroll helper
template <int I> struct Ic { static constexpr int v = I; };
template <int I, int N, typename F>
__device__ __forceinline__ void u_impl(F&& f) {
  if constexpr (I < N) { f(Ic<I>{}); u_impl<I + 1, N>(f); }
}
template <int N, typename F>
__device__ __forceinline__ void u_for(F&& f) { u_impl<0, N>(f); }

// complex mul: (ar*br - ai*bi, ar*bi + ai*br) = pk_mul + pk_fma
__device__ __forceinline__ v2 cmul(v2 a, v2 b) {
  v2 p = a.xx * b;
  return __builtin_elementwise_fma(mk2(-a.y, a.y), b.yx, p);
}
// a * conj(b): (ar*br + ai*bi, ai*br - ar*bi)
__device__ __forceinline__ v2 cmulc(v2 a, v2 b) {
  v2 p = a.xx * mk2(b.x, -b.y);
  return __builtin_elementwise_fma(a.yy, b.yx, p);
}
__device__ __forceinline__ v2 fma2(float sg, v2 mine, v2 oth) {
  return __builtin_elementwise_fma(mk2(sg, sg), mine, oth);
}
// lane^1 / lane^2 exchange on the VALU pipe (DPP quad_perm; all 64 lanes)
template <int CTRL>
__device__ __forceinline__ float dppf(float v) {
  return __int_as_float(
      __builtin_amdgcn_mov_dpp(__float_as_int(v), CTRL, 0xF, 0xF, true));
}
template <int M>  // M = 1 or 2
__device__ __forceinline__ v2 shdpp(v2 v) {
  constexpr int CTRL = (M == 1) ? 0xB1 : 0x4E;
  return mk2(dppf<CTRL>(v.x), dppf<CTRL>(v.y));
}
// lane^4 / lane^8 exchange via explicit ds_swizzle (BitMode xor patterns)
template <int M>  // M = 4 or 8
__device__ __forceinline__ v2 shswz(v2 v) {
  constexpr int PAT = (M << 10) | 0x1F;
  return mk2(
      __int_as_float(__builtin_amdgcn_ds_swizzle(__float_as_int(v.x), PAT)),
      __int_as_float(__builtin_amdgcn_ds_swizzle(__float_as_int(v.y), PAT)));
}
__device__ __forceinline__ int rev7(int n) {
  return ((n & 1) << 6) | ((n & 2) << 4) | ((n & 4) << 2) | (n & 8) |
         ((n & 16) >> 2) | ((n & 32) >> 4) | ((n & 64) >> 6);
}
constexpr int crev3(int i) { return ((i & 1) << 2) | (i & 2) | ((i & 4) >> 2); }

// multiply by W8^i (literal): W8 = exp(-i*pi/4)
template <int i> __device__ __forceinline__ v2 mulW8(v2 t) {
  if constexpr (i == 0) return t;
  else if constexpr (i == 1) return (t + mk2(t.y, -t.x)) * RT2H;
  else if constexpr (i == 2) return mk2(t.y, -t.x);
  else return (mk2(t.y, -t.x) - t) * RT2H;
}
// multiply by conj(W8^i)
template <int i> __device__ __forceinline__ v2 mulW8c(v2 t) {
  if constexpr (i == 0) return t;
  else if constexpr (i == 1) return (t + mk2(-t.y, t.x)) * RT2H;
  else if constexpr (i == 2) return mk2(-t.y, t.x);
  else return (mk2(-t.y, t.x) - t) * RT2H;
}

struct Tw8 {
  v2 wq128, wq64, wq32;  // W128^q, W64^q, W32^q
  v2 ws8, ws4, ws2;      // upper-lane stage twiddles (lower lanes: 1)
  float sg8, sg4, sg2, sg1;  // butterfly signs per lane
};

// ---- FFT-128, ownership p = q + 16*i (q = lane&15, i = reg 0..7) ----
// DIF forward: natural position order in, bit-reversed order out.
__device__ __forceinline__ void dif8(v2 (&X)[8], const Tw8& T) {
  u_for<4>([&](auto I) {  // h=64 local: pairs (i, i+4); W = wq128 * W8^i
    constexpr int i = I.v;
    v2 A = X[i], B = X[i + 4];
    X[i] = A + B;
    X[i + 4] = mulW8<i>(cmul(A - B, T.wq128));
  });
  u_for<4>([&](auto I) {  // h=32 local: pairs (g, g+2); W = wq64 * W4^{g&1}
    constexpr int g = (I.v >> 1) * 4 + (I.v & 1);
    v2 A = X[g], B = X[g + 2];
    X[g] = A + B;
    v2 d = cmul(A - B, T.wq64);
    X[g + 2] = (g & 1) ? mk2(d.y, -d.x) : d;
  });
  u_for<4>([&](auto I) {  // h=16 local: pairs (e, e+1); W = wq32 (uniform)
    constexpr int e = I.v * 2;
    v2 A = X[e], B = X[e + 1];
    X[e] = A + B;
    X[e + 1] = cmul(A - B, T.wq32);
  });
  u_for<8>([&](auto I) {  // h=8 cross (mask 8, DS): W per-lane = ws8
    constexpr int i = I.v;
    v2 o = shswz<8>(X[i]);
    X[i] = cmul(fma2(T.sg8, X[i], o), T.ws8);
  });
  u_for<8>([&](auto I) {  // h=4 cross (mask 4, DS)
    constexpr int i = I.v;
    v2 o = shswz<4>(X[i]);
    X[i] = cmul(fma2(T.sg4, X[i], o), T.ws4);
  });
  u_for<8>([&](auto I) {  // h=2 cross (mask 2, DPP/VALU)
    constexpr int i = I.v;
    v2 o = shdpp<2>(X[i]);
    X[i] = cmul(fma2(T.sg2, X[i], o), T.ws2);
  });
  u_for<8>([&](auto I) {  // h=1 cross (mask 1, DPP/VALU): W = 1
    constexpr int i = I.v;
    v2 o = shdpp<1>(X[i]);
    X[i] = fma2(T.sg1, X[i], o);
  });
}

// Inverse (DIT): exact mirror network, conj twiddles; bitrev in, natural out.
__device__ __forceinline__ void dit8(v2 (&X)[8], const Tw8& T) {
  u_for<8>([&](auto I) {  // h=1 cross (DPP)
    constexpr int i = I.v;
    v2 o = shdpp<1>(X[i]);
    X[i] = fma2(T.sg1, X[i], o);
  });
  u_for<8>([&](auto I) {  // h=2 cross (DPP): u = mine*conj(ws2), exchange, fma
    constexpr int i = I.v;
    v2 u = cmulc(X[i], T.ws2);
    v2 o = shdpp<2>(u);
    X[i] = fma2(T.sg2, u, o);
  });
  u_for<8>([&](auto I) {  // h=4 cross (DS)
    constexpr int i = I.v;
    v2 u = cmulc(X[i], T.ws4);
    v2 o = shswz<4>(u);
    X[i] = fma2(T.sg4, u, o);
  });
  u_for<8>([&](auto I) {  // h=8 cross (DS)
    constexpr int i = I.v;
    v2 u = cmulc(X[i], T.ws8);
    v2 o = shswz<8>(u);
    X[i] = fma2(T.sg8, u, o);
  });
  u_for<4>([&](auto I) {  // h=16 local
    constexpr int e = I.v * 2;
    v2 A = X[e];
    v2 t = cmulc(X[e + 1], T.wq32);
    X[e] = A + t;
    X[e + 1] = A - t;
  });
  u_for<4>([&](auto I) {  // h=32 local: conj(W4^{g&1}) = +i for odd g
    constexpr int g = (I.v >> 1) * 4 + (I.v & 1);
    v2 A = X[g];
    v2 t0 = cmulc(X[g + 2], T.wq64);
    v2 t = (g & 1) ? mk2(-t0.y, t0.x) : t0;
    X[g] = A + t;
    X[g + 2] = A - t;
  });
  u_for<4>([&](auto I) {  // h=64 local: conj(W8^i) literal
    constexpr int i = I.v;
    v2 A = X[i];
    v2 t = mulW8c<i>(cmulc(X[i + 4], T.wq128));
    X[i] = A + t;
    X[i + 4] = A - t;
  });
}

// One block = one (k, mode). 1024 threads: q = t&15, gg = t>>4.
// PRE: T=exp(iV) preloaded from d_ws (else computed in-loop).
template <bool PRE>
__global__ __launch_bounds__(1024)
void msp_mode(const float* __restrict__ V, const v2* __restrict__ Texp,
              const float* __restrict__ Pre, const float* __restrict__ Pim,
              const int* __restrict__ pos, float* __restrict__ out) {
  __shared__ v2 fld[TM * PITCH];  // 133,120 B field buffer (no swizzle)
  __shared__ v2 hyb[TM];  // hy at index 16i+q (bit-rev storage: conflict-free)
  __shared__ v2 hxb[TM];  // hx*INV_N2 at natural column index cc

  const int t = threadIdx.x;
  const int k = blockIdx.x >> 2;
  const int m = blockIdx.x & 3;
  const int q = t & 15;   // segment: owns positions q + 16*i
  const int gg = t >> 4;  // row (phase R) / col (phase C) group, 0..63

  // per-thread twiddle constants
  Tw8 T;
  float s, c;
  const float qf = (float)q;
  __sincosf(-PIF * qf / 64.0f, &s, &c);  T.wq128 = mk2(c, s);
  __sincosf(-PIF * qf / 32.0f, &s, &c);  T.wq64  = mk2(c, s);
  __sincosf(-PIF * qf / 16.0f, &s, &c);  T.wq32  = mk2(c, s);
  if (q & 8) { __sincosf(-PIF * (float)(q & 7) / 8.0f, &s, &c); T.ws8 = mk2(c, s); }
  else T.ws8 = mk2(1.f, 0.f);
  if (q & 4) { __sincosf(-PIF * (float)(q & 3) / 4.0f, &s, &c); T.ws4 = mk2(c, s); }
  else T.ws4 = mk2(1.f, 0.f);
  T.ws2 = (q & 2) ? ((q & 1) ? mk2(0.f, -1.f) : mk2(1.f, 0.f)) : mk2(1.f, 0.f);
  T.sg8 = (q & 8) ? -1.f : 1.f;
  T.sg4 = (q & 4) ? -1.f : 1.f;
  T.sg2 = (q & 2) ? -1.f : 1.f;
  T.sg1 = (q & 1) ? -1.f : 1.f;

  const int rev4q =
      ((q & 1) << 3) | ((q & 2) << 1) | ((q & 4) >> 1) | ((q & 8) >> 3);

  // H tables (z-invariant): hyb[16i+q'] -> ky = 8*rev4(q') + rev3(i)
  if (t < TM) {
    const int qq = t & 15, ii = t >> 4;
    const int r4 = ((qq & 1) << 3) | ((qq & 2) << 1) | ((qq & 4) >> 1) |
                   ((qq & 8) >> 3);
    const int ky = 8 * r4 + crev3(ii);
    const int iy = ky - ((ky & 64) ? 128 : 0);
    float s0, c0;
    __sincosf(PKF * (float)(iy * iy), &s0, &c0);
    hyb[t] = mk2(c0, s0);
    const int kx = rev7(t);
    const int ixf = kx - ((kx & 64) ? 128 : 0);
    __sincosf(PKF * (float)(ixf * ixf), &s0, &c0);
    hxb[t] = mk2(c0 * INV_N2, s0 * INV_N2);
  }

  const int p0 = pos[2 * k];
  const int p1 = pos[2 * k + 1];

  // load probe mode m directly into the LDS field
#pragma unroll 1
  for (int h = 0; h < 2; ++h) {
    const int y = gg + 64 * h;
    const float* pr = Pre + (m * TM + y) * TM + q;
    const float* pi = Pim + (m * TM + y) * TM + q;
    u_for<8>([&](auto I) {
      constexpr int i = I.v;
      fld[y * PITCH + q + 16 * i] = mk2(pr[16 * i], pi[16 * i]);
    });
  }
  __syncthreads();

#pragma unroll 1
  for (int z = 0; z < TNZ; ++z) {
    // phase R: [rowI if z>0] -> T(z) -> rowF, per half
#pragma unroll 1
    for (int h = 0; h < 2; ++h) {
      const int y = gg + 64 * h;
      v2 X[8];
      u_for<8>([&](auto I) { X[I.v] = fld[y * PITCH + q + 16 * I.v]; });
      if (z > 0) dit8(X, T);
      const int off = ((z * TNY) + (p0 + y)) * TNX + p1 + q;
      if constexpr (PRE) {
        const v2* tb = Texp + off;
        u_for<8>([&](auto I) { X[I.v] = cmul(X[I.v], tb[16 * I.v]); });
      } else {
        const float* vb = V + off;
        u_for<8>([&](auto I) {
          constexpr int i = I.v;
          float v = vb[16 * i];
          float sv, cv;
          __sincosf(v, &sv, &cv);
          X[i] = cmul(X[i], mk2(cv, sv));
        });
      }
      dif8(X, T);
      u_for<8>([&](auto I) { fld[y * PITCH + q + 16 * I.v] = X[I.v]; });
    }
    __syncthreads();

    // phase C: colF -> [H -> colI] (or |.|^2 scatter on the last slice)
    const bool last = (z == TNZ - 1);
#pragma unroll 1
    for (int h = 0; h < 2; ++h) {
      const int cc = gg + 64 * h;
      v2 X[8];
      u_for<8>([&](auto I) { X[I.v] = fld[(q + 16 * I.v) * PITCH + cc]; });
      dif8(X, T);
      if (!last) {
        const v2 hxv = hxb[cc];  // broadcast within 16-lane groups
        u_for<8>([&](auto I) {   // H = hy[ky]*hx[kx]; INV_N2 folded in hx
          constexpr int i = I.v;
          X[i] = cmul(cmul(X[i], hyb[16 * i + q]), hxv);
        });
        dit8(X, T);
        u_for<8>([&](auto I) { fld[(q + 16 * I.v) * PITCH + cc] = X[I.v]; });
      } else {
        // |psi_f|^2 scattered to natural frequency (ky,kx'), float view.
        // ky = 8*rev4q + rev3(i); kx' = rev7(cc) ^ rev4q (bank-spread XOR).
        float* fldf = reinterpret_cast<float*>(fld);
        const int kxn = rev7(cc) ^ rev4q;
        u_for<8>([&](auto I) {
          constexpr int i = I.v;
          const int ky = 8 * rev4q + crev3(i);
          float v = fmaf(X[i].x, X[i].x, X[i].y * X[i].y);
          fldf[ky * (2 * PITCH) + kxn] = v;
        });
      }
    }
    __syncthreads();
  }

  // gather (linear, conflict-free, coalesced) and global atomic accumulate
  const float* fldf = reinterpret_cast<const float*>(fld);
  float* ob = out + k * (TM * TM);
#pragma unroll
  for (int ii = 0; ii < 16; ++ii) {
    const int idx = t + 1024 * ii;
    const int ky = idx >> 7, kx = idx & 127;
    const int kxn = kx ^ ((ky >> 3) & 15);
    atomicAdd(&ob[idx], fldf[ky * (2 * PITCH) + kxn]);
  }
}

__global__ __launch_bounds__(256) void texp_k(const float* __restrict__ V,
                                              v2* __restrict__ Texp, int n) {
  const int i = blockIdx.x * 256 + threadIdx.x;
  if (i < n) {
    float s, c;
    __sincosf(V[i], &s, &c);
    Texp[i] = mk2(c, s);
  }
}

__global__ __launch_bounds__(256) void zero_k(float4* __restrict__ p, int n4) {
  const int i = blockIdx.x * 256 + threadIdx.x;
  if (i < n4) p[i] = make_float4(0.f, 0.f, 0.f, 0.f);
}

__global__ __launch_bounds__(256) void sqrt_k(float* __restrict__ p, int n) {
  const int i = blockIdx.x * 256 + threadIdx.x;
  if (i < n) p[i] = sqrtf(EPSV + p[i] * INV_N2);  // ortho: 1/N^2 on |.|^2
}

}  // namespace

extern "C" void kernel_launch(void* const* d_in, const int* in_sizes, int n_in,
                              void* d_out, int out_size, void* d_ws, size_t ws_size,
                              hipStream_t stream) {
  (void)in_sizes; (void)n_in;
  const float* V = (const float*)d_in[0];
  const float* Pre = (const float*)d_in[1];
  const float* Pim = (const float*)d_in[2];
  const int* pos = (const int*)d_in[3];
  float* out = (float*)d_out;
  const int n = out_size;  // 256*128*128
  const int n4 = n >> 2;
  zero_k<<<dim3((n4 + 255) / 256), dim3(256), 0, stream>>>((float4*)out, n4);

  const int nT = TNZ * TNY * TNX;
  const size_t texp_bytes = (size_t)nT * sizeof(v2);
  if (ws_size >= texp_bytes) {
    v2* Texp = (v2*)d_ws;
    texp_k<<<dim3((nT + 255) / 256), dim3(256), 0, stream>>>(V, Texp, nT);
    msp_mode<true><<<dim3(1024), dim3(1024), 0, stream>>>(V, Texp, Pre, Pim,
                                                          pos, out);
  } else {
    msp_mode<false><<<dim3(1024), dim3(1024), 0, stream>>>(V, nullptr, Pre,
                                                           Pim, pos, out);
  }
  sqrt_k<<<dim3((n + 255) / 256), dim3(256), 0, stream>>>(out, n);
}